// Round 14
// baseline (491.561 us; speedup 1.0000x reference)
//
#include <hip/hip_runtime.h>
#include <hip/hip_bf16.h>

#define H   128
#define RR  8
#define NN  8192
#define BB  64
#define LL  48
#define EE  65536
#define NPG 128          // nodes per graph (N/B)
#define VA  64
#define NSEG (NN*RR)     // 65536

typedef unsigned short u16;
typedef unsigned int   u32;

__device__ __forceinline__ float b2f(u16 u) {
    union { u32 i; float f; } v; v.i = ((u32)u) << 16; return v.f;
}
__device__ __forceinline__ u16 f2b(float f) {
    union { float f; u32 i; } v; v.f = f;
    u32 x = v.i;
    return (u16)((x + 0x7fffu + ((x >> 16) & 1u)) >> 16);
}
__device__ __forceinline__ float2 up2(u32 p) {
    union { u32 i; float f; } a, b;
    a.i = p << 16; b.i = p & 0xffff0000u;
    return make_float2(a.f, b.f);
}
__device__ __forceinline__ u32 pk2(float a, float b) {
    return ((u32)f2b(b) << 16) | (u32)f2b(a);
}

typedef __attribute__((ext_vector_type(8))) short bf16x8;
typedef __attribute__((ext_vector_type(4))) float f32x4;

// ---------------- init: zero seg counters + embed nodes (f32 out) ----------------
__global__ __launch_bounds__(256) void k_init(const int* __restrict__ nodeTypes,
                                              const float* __restrict__ emb_nodes,
                                              float* __restrict__ x0,
                                              int* __restrict__ fill) {
    int idx = blockIdx.x * 256 + threadIdx.x;
    if (idx < NSEG) fill[idx] = 0;
    if (idx < NN * H) {
        int n = idx >> 7, h = idx & (H - 1);
        x0[idx] = emb_nodes[(size_t)nodeTypes[n] * H + h];
    }
}

// ---------------- histogram of (dst,rel) segments ----------------
__global__ __launch_bounds__(256) void k_hist(const int* __restrict__ edge_index,
                                              const int* __restrict__ edge_attr,
                                              int* __restrict__ fill) {
    int e = blockIdx.x * 256 + threadIdx.x;
    if (e < EE) {
        int seg = edge_index[EE + e] * RR + edge_attr[e];
        atomicAdd(&fill[seg], 1);
    }
}

// ---------------- 3-stage parallel exclusive scan over 65536 counts ----------------
__global__ __launch_bounds__(256) void k_scan1(const int* __restrict__ fill,
                                               int* __restrict__ bsum) {
    __shared__ int red[4];
    int tid = threadIdx.x, lane = tid & 63, wv = tid >> 6;
    int v = fill[blockIdx.x * 256 + tid];
#pragma unroll
    for (int off = 32; off >= 1; off >>= 1) v += __shfl_down(v, off, 64);
    if (lane == 0) red[wv] = v;
    __syncthreads();
    if (tid == 0) bsum[blockIdx.x] = red[0] + red[1] + red[2] + red[3];
}

__global__ __launch_bounds__(256) void k_scan2(const int* __restrict__ bsum,
                                               int* __restrict__ boff,
                                               int* __restrict__ rowptr) {
    __shared__ int s[256];
    int tid = threadIdx.x;
    int v0 = bsum[tid];
    s[tid] = v0;
    __syncthreads();
    for (int off = 1; off < 256; off <<= 1) {
        int v = (tid >= off) ? s[tid - off] : 0;
        __syncthreads();
        s[tid] += v;
        __syncthreads();
    }
    boff[tid] = s[tid] - v0;           // exclusive
    if (tid == 255) rowptr[NSEG] = s[255];
}

__global__ __launch_bounds__(256) void k_scan3(const int* __restrict__ boff,
                                               int* __restrict__ fill,
                                               int* __restrict__ rowptr) {
    __shared__ int s[256];
    int tid = threadIdx.x;
    int g = blockIdx.x * 256 + tid;
    int c = fill[g];
    s[tid] = c;
    __syncthreads();
    for (int off = 1; off < 256; off <<= 1) {
        int v = (tid >= off) ? s[tid - off] : 0;
        __syncthreads();
        s[tid] += v;
        __syncthreads();
    }
    int r = boff[blockIdx.x] + s[tid] - c;
    rowptr[g] = r;
    fill[g] = r;    // becomes scatter cursor
}

// ---------------- scatter edges into CSR (+ per-edge seg map) ----------------
__global__ __launch_bounds__(256) void k_scatter(const int* __restrict__ edge_index,
                                                 const int* __restrict__ edge_attr,
                                                 int* __restrict__ fill,
                                                 int* __restrict__ colidx,
                                                 int* __restrict__ esegG) {
    int e = blockIdx.x * 256 + threadIdx.x;
    if (e < EE) {
        int seg = edge_index[EE + e] * RR + edge_attr[e];
        int pos = atomicAdd(&fill[seg], 1);
        colidx[pos] = edge_index[e];   // src
        esegG[pos]  = seg;
    }
}

// ---------------- merged weight prep: fragment-tiled WT + W_ih bf16 + hGsum zero ----------------
// WTt[li][tile(4)][ks(36)][sub(2)][lane(64)][j(8)] ; col = tile*32+sub*16+(lane&15),
// k = ks*32+(lane>>4)*8+j ; k<1024 -> rel[li][k>>7][k&127][col], else root[li][k-1024][col]
__global__ __launch_bounds__(256) void k_wprep(const float* __restrict__ rel,
                                               const float* __restrict__ root,
                                               const float* __restrict__ w_ih,
                                               u16* __restrict__ WTt,
                                               u16* __restrict__ WTih,
                                               float* __restrict__ hGsum) {
    int idx = blockIdx.x * 256 + threadIdx.x;
    if (idx < 384 * H) WTih[idx] = f2b(w_ih[idx]);
    if (idx < BB * H) hGsum[idx] = 0.f;
    if (idx >= 3 * 147456) return;
    int li  = idx / 147456;
    int rem = idx - li * 147456;
    int tile = rem / 36864;
    int r2   = rem - tile * 36864;
    int ks   = r2 / 1024;
    int r3   = r2 - ks * 1024;
    int sub  = r3 >> 9;
    int r4   = r3 & 511;
    int lane = r4 >> 3, j = r4 & 7;
    int col = tile * 32 + sub * 16 + (lane & 15);
    int k   = ks * 32 + (lane >> 4) * 8 + j;
    float v;
    if (k < 1024) v = rel[(((size_t)li * RR + (k >> 7)) * H + (k & 127)) * H + col];
    else          v = root[((size_t)li * H + (k - 1024)) * H + col];
    WTt[idx] = f2b(v);
}

// ---------------- one RGCN layer: batched edge-parallel gather + bf16 MFMA GEMM + relu ----------------
#define RGN 16           // nodes per block; grid = 512
#define EPRE 512

__global__ __launch_bounds__(256) void k_rgcn(const float* __restrict__ xin,
                                              float* __restrict__ xout,
                                              const u16* __restrict__ WTt,    // fragment-tiled
                                              const float* __restrict__ bias, // [H]
                                              const int* __restrict__ rowptr,
                                              const int* __restrict__ colidx,
                                              const int* __restrict__ esegG,
                                              float* __restrict__ hGsum) {   // null except L3
    __shared__ float Af[RGN][1160];        // 74.24 KB f32 staging (stride-padded)
    __shared__ int begs[RGN * RR + 1];
    __shared__ int eidx[EPRE];
    __shared__ int eseg[EPRE];
    u32* ab = (u32*)&Af[0][0];             // bf16-packed overlay, row stride 580 u32
    int tid = threadIdx.x, wv = tid >> 6, lane = tid & 63;
    int n0 = blockIdx.x * RGN, segbase = n0 * RR;

    if (tid <= RGN * RR) begs[tid] = rowptr[segbase + tid];
    for (int i = tid; i < RGN * 256; i += 256) {
        int row = i >> 8, q = i & 255;
        *(float4*)&Af[row][q * 4] = make_float4(0.f, 0.f, 0.f, 0.f);
    }
    __syncthreads();
    int E0 = begs[0], ne = begs[RGN * RR] - E0;
    for (int i = tid; i < ne && i < EPRE; i += 256) {
        eidx[i] = colidx[E0 + i];
        eseg[i] = esegG[E0 + i];
    }
    __syncthreads();

    // phase A: edge-parallel gather, 8 loads in flight before the atomics
    for (int i0 = wv * 8; i0 < ne; i0 += 32) {
        int ecnt = ne - i0; if (ecnt > 8) ecnt = 8;
        float2 vv[8]; int sl8[8];
#pragma unroll
        for (int u = 0; u < 8; ++u) {
            if (u < ecnt) {
                int e = i0 + u, src, sl;
                if (e < EPRE) { src = eidx[e];        sl = eseg[e] - segbase; }
                else          { src = colidx[E0 + e]; sl = esegG[E0 + e] - segbase; }
                vv[u] = ((const float2*)(xin + (size_t)src * H))[lane];
                sl8[u] = sl;
            }
        }
#pragma unroll
        for (int u = 0; u < 8; ++u) {
            if (u < ecnt) {
                float* dst = &Af[sl8[u] >> 3][((sl8[u] & 7) << 7) + 2 * lane];
                atomicAdd(dst, vv[u].x);
                atomicAdd(dst + 1, vv[u].y);
            }
        }
    }
    __syncthreads();

    // phase B: mean + root append, pack to bf16 pairs (held in regs across barrier)
    int rown = tid >> 4, sbase = tid & 15;
    u32 pk[36];
#pragma unroll
    for (int i = 0; i < 36; ++i) {
        int s = sbase + (i << 4);
        int k0 = s << 1;
        float v0, v1;
        if (k0 < 1024) {
            int r = k0 >> 7;
            int cnt = begs[rown * RR + r + 1] - begs[rown * RR + r];
            float inv = 1.f / fmaxf((float)cnt, 1.f);
            v0 = Af[rown][k0] * inv;
            v1 = Af[rown][k0 + 1] * inv;
        } else {
            const float* xr = xin + (size_t)(n0 + rown) * H + (k0 - 1024);
            v0 = xr[0];
            v1 = xr[1];
        }
        pk[i] = pk2(v0, v1);
    }
    __syncthreads();
#pragma unroll
    for (int i = 0; i < 36; ++i)
        ab[rown * 580 + sbase + (i << 4)] = pk[i];
    __syncthreads();

    // MFMA GEMM: wave = 32-col tile; 36 ksteps of 16x16x32 bf16, 2 n-subtiles.
    int m = lane & 15, quad = lane >> 4;
    int colbase = wv * 32;
    const u32* aP = ab + m * 580 + quad * 4;
    const u32* bT = (const u32*)WTt + (size_t)wv * 36 * 512 + lane * 4;
    f32x4 acc0 = {0.f, 0.f, 0.f, 0.f}, acc1 = {0.f, 0.f, 0.f, 0.f};
    for (int ks = 0; ks < 36; ++ks) {
        bf16x8 a  = *(const bf16x8*)(aP + ks * 16);
        bf16x8 b0 = *(const bf16x8*)(bT + ks * 512);         // sub 0
        bf16x8 b1 = *(const bf16x8*)(bT + ks * 512 + 256);   // sub 1
        acc0 = __builtin_amdgcn_mfma_f32_16x16x32_bf16(a, b0, acc0, 0, 0, 0);
        acc1 = __builtin_amdgcn_mfma_f32_16x16x32_bf16(a, b1, acc1, 0, 0, 0);
    }
    int c0 = colbase + m, c1 = c0 + 16;
    float bv0 = bias[c0], bv1 = bias[c1];
    float so0 = 0.f, so1 = 0.f;
#pragma unroll
    for (int rg = 0; rg < 4; ++rg) {
        int n = n0 + quad * 4 + rg;
        float o0 = fmaxf(acc0[rg] + bv0, 0.f);
        float o1 = fmaxf(acc1[rg] + bv1, 0.f);
        xout[(size_t)n * H + c0] = o0;
        xout[(size_t)n * H + c1] = o1;
        so0 += o0; so1 += o1;
    }
    if (hGsum) {      // fused mean-pool partial sums (layer 3 only)
        so0 += __shfl_xor(so0, 16, 64);
        so0 += __shfl_xor(so0, 32, 64);
        so1 += __shfl_xor(so1, 16, 64);
        so1 += __shfl_xor(so1, 32, 64);
        if (quad == 0) {
            int g = n0 >> 7;
            atomicAdd(&hGsum[g * H + c0], so0);
            atomicAdd(&hGsum[g * H + c1], so1);
        }
    }
}

// ---------------- action head (reads fused pool sums; writes divided hG) ----------------
__global__ __launch_bounds__(128) void k_pool_act(const float* __restrict__ hGsum,
                                                  const int* __restrict__ nodes_bs,
                                                  const float* __restrict__ linA_w,
                                                  const float* __restrict__ linA_b,
                                                  const float* __restrict__ linAf_w,
                                                  const float* __restrict__ linAf_b,
                                                  float* __restrict__ hG,
                                                  float* __restrict__ out) {
    __shared__ float hgs[H], t1[H];
    int b = blockIdx.x, h = threadIdx.x;
    float hg = hGsum[(size_t)b * H + h] / (float)nodes_bs[b];
    hG[(size_t)b * H + h] = hg;
    hgs[h] = hg;
    __syncthreads();
    float acc = linA_b[h];
    const float* wr = linA_w + (size_t)h * H;
    for (int k = 0; k < H; ++k) acc += wr[k] * hgs[k];
    t1[h] = fmaxf(acc, 0.f);
    __syncthreads();
    if (h < VA) {
        float a = linAf_b[h];
        const float* w2 = linAf_w + (size_t)h * H;
        for (int k = 0; k < H; ++k) a += w2[k] * t1[k];
        out[(size_t)b * VA + h] = a;
    }
}

// ---------------- sequence pooling -> SHIFTED GRU input igG ----------------
__global__ __launch_bounds__(256) void k_seqpool(const float* __restrict__ xf,
                                                 const float* __restrict__ seq,
                                                 const float* __restrict__ emb_actions,
                                                 const int* __restrict__ action_input,
                                                 float* __restrict__ igG) {
    __shared__ float xg[64][H];        // 32 KB
    __shared__ u16 lists[LL][64];      // 6 KB
    __shared__ int cnts[LL];
    int b = blockIdx.x, tid = threadIdx.x;
    int col = tid & 127, tg = tid >> 7;
    float acc[24];
#pragma unroll
    for (int m = 0; m < 24; ++m) acc[m] = 0.f;

    for (int chunk = 0; chunk < 2; ++chunk) {
        int i0 = b * NPG + chunk * 64;
        __syncthreads();
        if (tid < LL) cnts[tid] = 0;
        __syncthreads();
        for (int idx = tid; idx < 64 * H / 4; idx += 256)
            ((float4*)&xg[0][0])[idx] = ((const float4*)(xf + (size_t)i0 * H))[idx];
        for (int idx = tid; idx < 64 * LL; idx += 256) {
            int i = idx / LL, t = idx - i * LL;
            if (seq[(size_t)(i0 + i) * LL + t] != 0.f) {
                int p = atomicAdd(&cnts[t], 1);
                lists[t][p] = (u16)i;
            }
        }
        __syncthreads();
        for (int m = 0; m < 24; ++m) {
            int t = tg + 2 * m;
            int c = cnts[t];
            float a = acc[m];
            for (int p = 0; p < c; ++p) a += xg[lists[t][p]][col];
            acc[m] = a;
        }
    }
    if (tid < H)
        igG[((size_t)b * LL) * H + tid] = emb_actions[(size_t)action_input[b] * H + tid];
#pragma unroll
    for (int m = 0; m < 24; ++m) {
        int t = tg + 2 * m;
        if (t < LL - 1)
            igG[((size_t)b * LL + t + 1) * H + col] = acc[m];
    }
}

// ---------------- xw GEMM: xwG[3072][384] = igG @ W_ih^T + b_ih (bf16 out, MFMA) ----------------
__global__ __launch_bounds__(256) void k_xw(const float* __restrict__ igG,
                                            const u16* __restrict__ WTih,
                                            const float* __restrict__ b_ih,
                                            u16* __restrict__ xwG) {
    __shared__ u32 ab[16 * 68];        // 4.35 KB, stride 68
    int tid = threadIdx.x, wv = tid >> 6, lane = tid & 63;
    int n0 = blockIdx.x * 16;
    for (int s = tid; s < 16 * 64; s += 256) {
        int row = s >> 6, kp = s & 63;
        float2 v = *(const float2*)(igG + (size_t)(n0 + row) * H + 2 * kp);
        ab[row * 68 + kp] = pk2(v.x, v.y);
    }
    __syncthreads();
    int m = lane & 15, quad = lane >> 4;
    const u32* aP = ab + m * 68 + quad * 4;
    f32x4 acc[6];
#pragma unroll
    for (int i = 0; i < 6; ++i) acc[i] = (f32x4){0.f, 0.f, 0.f, 0.f};
#pragma unroll
    for (int ks = 0; ks < 4; ++ks) {
        bf16x8 a = *(const bf16x8*)(aP + ks * 16);
#pragma unroll
        for (int tc = 0; tc < 6; ++tc) {
            int colr = wv * 96 + tc * 16 + m;
            bf16x8 bfr = *(const bf16x8*)((const u32*)WTih + (size_t)colr * 64 + quad * 4 + ks * 16);
            acc[tc] = __builtin_amdgcn_mfma_f32_16x16x32_bf16(a, bfr, acc[tc], 0, 0, 0);
        }
    }
#pragma unroll
    for (int tc = 0; tc < 6; ++tc) {
        int c = wv * 96 + tc * 16 + m;
        float bv = b_ih[c];
#pragma unroll
        for (int rg = 0; rg < 4; ++rg) {
            int r = n0 + quad * 4 + rg;
            xwG[(size_t)r * 384 + c] = f2b(acc[tc][rg] + bv);
        }
    }
}

// ---------------- GRU: sequential steps only ----------------
__global__ __launch_bounds__(768) void k_gru(const u16* __restrict__ xwG,
                                             const float* __restrict__ hG,
                                             const float* __restrict__ w_hh,
                                             const float* __restrict__ b_hh,
                                             const int* __restrict__ len_seq,
                                             float* __restrict__ soutG) {
    __shared__ float xws[LL][3 * H];    // 73.7 KB
    __shared__ float hbuf[H];
    __shared__ float gh[3 * H];
    int b = blockIdx.x, tid = threadIdx.x;

    const u16* src = xwG + (size_t)b * LL * 384;
    float* xf = &xws[0][0];
    for (int idx = tid; idx < LL * 384; idx += 768) xf[idx] = b2f(src[idx]);
    if (tid < H) hbuf[tid] = hG[(size_t)b * H + tid];

    int j = tid >> 1, half = tid & 1;
    u32 wh[32];
    {
        const float* wp = w_hh + (size_t)j * H + 2 * half;   // elements 4k+2h, 4k+2h+1
#pragma unroll
        for (int k = 0; k < 32; ++k) wh[k] = pk2(wp[4 * k], wp[4 * k + 1]);
    }
    float bhh = b_hh[j];
    int ls = len_seq[b];
    __syncthreads();

    for (int t = 0; t < LL; ++t) {
        const float* hb = hbuf + 2 * half;
        float a = 0.f;
#pragma unroll
        for (int k = 0; k < 32; ++k) {
            float2 w = up2(wh[k]);
            float2 h2 = *(const float2*)&hb[4 * k];
            a += w.x * h2.x + w.y * h2.y;
        }
        a += __shfl_xor(a, 1, 64);
        if (half == 0) gh[j] = a + bhh;
        __syncthreads();
        if (tid < H) {
            float rg = 1.f / (1.f + __expf(-(xws[t][tid] + gh[tid])));
            float zg = 1.f / (1.f + __expf(-(xws[t][tid + H] + gh[tid + H])));
            float ng = tanhf(xws[t][tid + 2 * H] + rg * gh[tid + 2 * H]);
            float hnew = (1.f - zg) * ng + zg * hbuf[tid];
            hbuf[tid] = hnew;
            soutG[((size_t)b * LL + t) * H + tid] = (t < ls) ? hnew : 0.f;
        }
        __syncthreads();
    }
}

// ---------------- A2[row,:] = W1a @ sout[row]  (rows = b*48+t), f32 out ----------------
__global__ __launch_bounds__(256) void k_a2(const float* __restrict__ soutG,
                                            const float* __restrict__ linN_w,
                                            float* __restrict__ A2) {
    __shared__ float wb[32][130];
    __shared__ float xl[16][H];
    int tid = threadIdx.x;
    int n0 = blockIdx.x * 16;
    for (int idx = tid; idx < 16 * H; idx += 256)
        xl[idx >> 7][idx & 127] = soutG[(size_t)n0 * H + idx];
    int col = tid & 127, g = tid >> 7;
    float acc[8] = {0.f, 0.f, 0.f, 0.f, 0.f, 0.f, 0.f, 0.f};
    for (int c = 0; c < 4; ++c) {
        int k0 = c * 32;
        __syncthreads();
        for (int idx = tid; idx < 32 * H; idx += 256) {
            int r = idx >> 5, kk = idx & 31;
            wb[kk][r] = linN_w[(size_t)r * (2 * H) + k0 + kk];
        }
        __syncthreads();
#pragma unroll
        for (int kk = 0; kk < 32; ++kk) {
            float w = wb[kk][col];
#pragma unroll
            for (int j = 0; j < 8; ++j) acc[j] += xl[g * 8 + j][k0 + kk] * w;
        }
    }
#pragma unroll
    for (int j = 0; j < 8; ++j)
        A2[(size_t)(n0 + g * 8 + j) * H + col] = acc[j];
}

// ---------------- Bx[n,:] = W1b @ x[n] + linN_b (bf16 out) ----------------
__global__ __launch_bounds__(256) void k_bx(const float* __restrict__ xf,
                                            const float* __restrict__ linN_w,
                                            const float* __restrict__ linN_b,
                                            u16* __restrict__ BxU) {
    __shared__ float wb[32][130];
    __shared__ float xl[16][H];
    int tid = threadIdx.x;
    int n0 = blockIdx.x * 16;
    for (int idx = tid; idx < 16 * H; idx += 256)
        xl[idx >> 7][idx & 127] = xf[(size_t)n0 * H + idx];
    int col = tid & 127, g = tid >> 7;
    float bv = linN_b[col];
    float acc[8] = {bv, bv, bv, bv, bv, bv, bv, bv};
    for (int c = 0; c < 4; ++c) {
        int k0 = c * 32;
        __syncthreads();
        for (int idx = tid; idx < 32 * H; idx += 256) {
            int r = idx >> 5, kk = idx & 31;
            wb[kk][r] = linN_w[(size_t)r * (2 * H) + H + k0 + kk];
        }
        __syncthreads();
#pragma unroll
        for (int kk = 0; kk < 32; ++kk) {
            float w = wb[kk][col];
#pragma unroll
            for (int j = 0; j < 8; ++j) acc[j] += xl[g * 8 + j][k0 + kk] * w;
        }
    }
#pragma unroll
    for (int j = 0; j < 8; ++j)
        BxU[(size_t)(n0 + g * 8 + j) * H + col] = f2b(acc[j]);
}

// ---------------- logits[n][t] = sum_k w2[k]*relu(A2[t][k]+Bx[n][k]) ----------------
__global__ __launch_bounds__(256) void k_logits(const float* __restrict__ A2,
                                                const u16* __restrict__ BxU,
                                                const float* __restrict__ linNf_w,
                                                float* __restrict__ logits) {
    __shared__ float a2s[LL][130];
    __shared__ float bxs[16][130];
    __shared__ float w2s[H];
    int tid = threadIdx.x;
    int g = blockIdx.x >> 3, tile = blockIdx.x & 7;
    int n0g = g * NPG + tile * 16;

    for (int i2 = tid; i2 < LL * 64; i2 += 256) {
        int r = i2 >> 6, c2 = i2 & 63;
        *(float2*)&a2s[r][2 * c2] = *(const float2*)(A2 + ((size_t)g * LL + r) * H + 2 * c2);
    }
    for (int iu = tid; iu < 16 * 64; iu += 256) {
        int r = iu >> 6, c = iu & 63;
        float2 v = up2(((const u32*)BxU)[(size_t)(n0g + r) * 64 + c]);
        *(float2*)&bxs[r][2 * c] = v;
    }
    if (tid < H) w2s[tid] = linNf_w[tid];
    __syncthreads();

    int n = tid & 15, tt = tid >> 4;
#pragma unroll
    for (int pass = 0; pass < 3; ++pass) {
        int t = tt + 16 * pass;
        float acc = 0.f;
#pragma unroll
        for (int kp = 0; kp < 64; ++kp) {
            float2 a2 = *(const float2*)&a2s[t][2 * kp];
            float2 bx = *(const float2*)&bxs[n][2 * kp];
            float2 w  = *(const float2*)&w2s[2 * kp];
            acc += w.x * fmaxf(a2.x + bx.x, 0.f) + w.y * fmaxf(a2.y + bx.y, 0.f);
        }
        logits[(size_t)(n0g + n) * LL + t] = acc;
    }
}

// ---------------- per-(graph,t) softmax over nodes; write output ----------------
__global__ __launch_bounds__(256) void k_softmax(const float* __restrict__ logits,
                                                 float* __restrict__ out) {
    __shared__ float lg[NPG][LL + 1];
    __shared__ float pm[4][LL], ps[4][LL];
    __shared__ float mv[LL], inv[LL];
    int b = blockIdx.x, tid = threadIdx.x;
    int n0 = b * NPG;
    for (int idx = tid; idx < NPG * LL; idx += 256) {
        int n = idx / LL, t = idx - n * LL;
        lg[n][t] = logits[(size_t)n0 * LL + idx];
    }
    __syncthreads();
    int t = tid & 63, seg = tid >> 6;
    if (t < LL) {
        float m = -1e30f;
        int nb = seg * 32;
        for (int n = nb; n < nb + 32; ++n) m = fmaxf(m, lg[n][t]);
        pm[seg][t] = m;
    }
    __syncthreads();
    if (tid < LL)
        mv[tid] = fmaxf(fmaxf(pm[0][tid], pm[1][tid]), fmaxf(pm[2][tid], pm[3][tid]));
    __syncthreads();
    if (t < LL) {
        float m = mv[t], s = 0.f;
        int nb = seg * 32;
        for (int n = nb; n < nb + 32; ++n) {
            float e = __expf(lg[n][t] - m);
            lg[n][t] = e;
            s += e;
        }
        ps[seg][t] = s;
    }
    __syncthreads();
    if (tid < LL)
        inv[tid] = 1.f / (ps[0][tid] + ps[1][tid] + ps[2][tid] + ps[3][tid]);
    __syncthreads();
    for (int idx = tid; idx < NPG * LL; idx += 256) {
        int n = idx / LL, tc = idx - n * LL;
        out[(size_t)BB * VA + (size_t)n0 * LL + idx] = lg[n][tc] * inv[tc];
    }
}

// ---------------- launch ----------------
extern "C" void kernel_launch(void* const* d_in, const int* in_sizes, int n_in,
                              void* d_out, int out_size, void* d_ws, size_t ws_size,
                              hipStream_t stream) {
    (void)in_sizes; (void)n_in; (void)out_size; (void)ws_size;
    const int*   nodeTypes    = (const int*)d_in[0];
    const int*   edge_index   = (const int*)d_in[1];
    const int*   edge_attr    = (const int*)d_in[2];
    const int*   nodes_bs     = (const int*)d_in[4];
    const int*   len_seq      = (const int*)d_in[5];
    const float* seq_in       = (const float*)d_in[6];
    const int*   action_input = (const int*)d_in[7];
    const float* emb_nodes    = (const float*)d_in[8];
    const float* emb_actions  = (const float*)d_in[9];
    const float* rgcn_rel     = (const float*)d_in[10];
    const float* rgcn_root    = (const float*)d_in[11];
    const float* rgcn_bias    = (const float*)d_in[12];
    const float* gru_w_ih     = (const float*)d_in[13];
    const float* gru_w_hh     = (const float*)d_in[14];
    const float* gru_b_ih     = (const float*)d_in[15];
    const float* gru_b_hh     = (const float*)d_in[16];
    const float* linA_w       = (const float*)d_in[17];
    const float* linA_b       = (const float*)d_in[18];
    const float* linAf_w      = (const float*)d_in[19];
    const float* linAf_b      = (const float*)d_in[20];
    const float* linN_w       = (const float*)d_in[21];
    const float* linN_b       = (const float*)d_in[22];
    const float* linNf_w      = (const float*)d_in[23];
    // linNf_b cancels in the softmax

    char* w = (char*)d_ws;
    float* x0      = (float*)(w + 0);          // [0,4MB) emb ping; dead after rgcn L3
    u16*   xwG     = (u16*)  (w + 0);          //   overlay (after L3): [0, 2,359,296)
    float* logitsW = (float*)(w + 0);          //   overlay (after k_gru): [0, 1,572,864)
    float* soutG   = (float*)(w + 2359296);    //   overlay (after L3): [.., 3,932,160)
    float* x1      = (float*)(w + 4194304);    // [4MB,8MB) final x f32 (live to end)
    float* igG     = (float*)(w + 8388608);    // [8MB, 9,961,472) shifted GRU input
    float* A2      = (float*)(w + 8388608);    //   overlay (igG dead before k_a2)
    u16*   BxU     = (u16*)  (w + 9961472);    // [9,961,472, 12,058,624)
    int*   bsum    = (int*)  (w + 9961472);    //   overlay on BxU (dead until k_bx)
    int*   boff    = (int*)  (w + 9962496);    //   overlay on BxU + 1 KB
    float* hGsum   = (float*)(w + 9969664);    //   overlay on BxU + 8 KB (dead by k_bx)
    int*   rowptr  = (int*)  (w + 11567104);   // dead after rgcn L3
    int*   fill    = (int*)  (w + 11829760);   // dead after scatter
    u16*   WTih    = (u16*)  (w + 11829760);   //   overlay fill; dead after k_xw
    float* hG      = (float*)(w + 12058624);   // 32 KB
    int*   colidx  = (int*)  (w + 12091904);   // dead after rgcn L3
    int*   esegG   = (int*)  (w + 12354048);   // dead after rgcn L3
    u16*   WT      = (u16*)  (w + 12616192);   // rgcn weights bf16 (tiled), 884,736 B

    float* out_f = (float*)d_out;

    k_init<<<dim3(4096), dim3(256), 0, stream>>>(nodeTypes, emb_nodes, x0, fill);
    k_hist<<<dim3(256), dim3(256), 0, stream>>>(edge_index, edge_attr, fill);
    k_scan1<<<dim3(256), dim3(256), 0, stream>>>(fill, bsum);
    k_scan2<<<dim3(1), dim3(256), 0, stream>>>(bsum, boff, rowptr);
    k_scan3<<<dim3(256), dim3(256), 0, stream>>>(boff, fill, rowptr);
    k_scatter<<<dim3(256), dim3(256), 0, stream>>>(edge_index, edge_attr, fill, colidx, esegG);
    k_wprep<<<dim3(1728), dim3(256), 0, stream>>>(rgcn_rel, rgcn_root, gru_w_ih,
                                                  WT, WTih, hGsum);

    const int rg_grid = NN / RGN;   // 512
    k_rgcn<<<dim3(rg_grid), dim3(256), 0, stream>>>(x0, x1,
        WT + 0 * 147456, rgcn_bias + 0 * H, rowptr, colidx, esegG, nullptr);
    k_rgcn<<<dim3(rg_grid), dim3(256), 0, stream>>>(x1, x0,
        WT + 1 * 147456, rgcn_bias + 1 * H, rowptr, colidx, esegG, nullptr);
    k_rgcn<<<dim3(rg_grid), dim3(256), 0, stream>>>(x0, x1,
        WT + 2 * 147456, rgcn_bias + 2 * H, rowptr, colidx, esegG, hGsum);
    // x_final = x1 (x0 region free from here)

    k_pool_act<<<dim3(BB), dim3(128), 0, stream>>>(hGsum, nodes_bs, linA_w, linA_b,
                                                   linAf_w, linAf_b, hG, out_f);
    k_seqpool<<<dim3(BB), dim3(256), 0, stream>>>(x1, seq_in, emb_actions, action_input, igG);
    k_xw<<<dim3(BB * LL / 16), dim3(256), 0, stream>>>(igG, WTih, gru_b_ih, xwG);
    k_gru<<<dim3(BB), dim3(768), 0, stream>>>(xwG, hG, gru_w_hh, gru_b_hh, len_seq, soutG);
    k_a2<<<dim3(BB * LL / 16), dim3(256), 0, stream>>>(soutG, linN_w, A2);
    k_bx<<<dim3(NN / 16), dim3(256), 0, stream>>>(x1, linN_w, linN_b, BxU);
    k_logits<<<dim3(BB * 8), dim3(256), 0, stream>>>(A2, BxU, linNf_w, logitsW);
    k_softmax<<<dim3(BB), dim3(256), 0, stream>>>(logitsW, out_f);
}

// Round 15
// 467.448 us; speedup vs baseline: 1.0516x; 1.0516x over previous
//
#include <hip/hip_runtime.h>
#include <hip/hip_bf16.h>

#define H   128
#define RR  8
#define NN  8192
#define BB  64
#define LL  48
#define EE  65536
#define NPG 128          // nodes per graph (N/B)
#define VA  64
#define NSEG (NN*RR)     // 65536

typedef unsigned short u16;
typedef unsigned int   u32;

__device__ __forceinline__ float b2f(u16 u) {
    union { u32 i; float f; } v; v.i = ((u32)u) << 16; return v.f;
}
__device__ __forceinline__ u16 f2b(float f) {
    union { float f; u32 i; } v; v.f = f;
    u32 x = v.i;
    return (u16)((x + 0x7fffu + ((x >> 16) & 1u)) >> 16);
}
__device__ __forceinline__ float2 up2(u32 p) {
    union { u32 i; float f; } a, b;
    a.i = p << 16; b.i = p & 0xffff0000u;
    return make_float2(a.f, b.f);
}
__device__ __forceinline__ u32 pk2(float a, float b) {
    return ((u32)f2b(b) << 16) | (u32)f2b(a);
}

typedef __attribute__((ext_vector_type(8))) short bf16x8;
typedef __attribute__((ext_vector_type(4))) float f32x4;

// ---------------- init: zero seg counters + embed nodes (f32 out) ----------------
__global__ __launch_bounds__(256) void k_init(const int* __restrict__ nodeTypes,
                                              const float* __restrict__ emb_nodes,
                                              float* __restrict__ x0,
                                              int* __restrict__ fill) {
    int idx = blockIdx.x * 256 + threadIdx.x;
    if (idx < NSEG) fill[idx] = 0;
    if (idx < NN * H) {
        int n = idx >> 7, h = idx & (H - 1);
        x0[idx] = emb_nodes[(size_t)nodeTypes[n] * H + h];
    }
}

// ---------------- histogram of (dst,rel) segments ----------------
__global__ __launch_bounds__(256) void k_hist(const int* __restrict__ edge_index,
                                              const int* __restrict__ edge_attr,
                                              int* __restrict__ fill) {
    int e = blockIdx.x * 256 + threadIdx.x;
    if (e < EE) {
        int seg = edge_index[EE + e] * RR + edge_attr[e];
        atomicAdd(&fill[seg], 1);
    }
}

// ---------------- 3-stage parallel exclusive scan over 65536 counts ----------------
__global__ __launch_bounds__(256) void k_scan1(const int* __restrict__ fill,
                                               int* __restrict__ bsum) {
    __shared__ int red[4];
    int tid = threadIdx.x, lane = tid & 63, wv = tid >> 6;
    int v = fill[blockIdx.x * 256 + tid];
#pragma unroll
    for (int off = 32; off >= 1; off >>= 1) v += __shfl_down(v, off, 64);
    if (lane == 0) red[wv] = v;
    __syncthreads();
    if (tid == 0) bsum[blockIdx.x] = red[0] + red[1] + red[2] + red[3];
}

__global__ __launch_bounds__(256) void k_scan2(const int* __restrict__ bsum,
                                               int* __restrict__ boff,
                                               int* __restrict__ rowptr) {
    __shared__ int s[256];
    int tid = threadIdx.x;
    int v0 = bsum[tid];
    s[tid] = v0;
    __syncthreads();
    for (int off = 1; off < 256; off <<= 1) {
        int v = (tid >= off) ? s[tid - off] : 0;
        __syncthreads();
        s[tid] += v;
        __syncthreads();
    }
    boff[tid] = s[tid] - v0;           // exclusive
    if (tid == 255) rowptr[NSEG] = s[255];
}

__global__ __launch_bounds__(256) void k_scan3(const int* __restrict__ boff,
                                               int* __restrict__ fill,
                                               int* __restrict__ rowptr) {
    __shared__ int s[256];
    int tid = threadIdx.x;
    int g = blockIdx.x * 256 + tid;
    int c = fill[g];
    s[tid] = c;
    __syncthreads();
    for (int off = 1; off < 256; off <<= 1) {
        int v = (tid >= off) ? s[tid - off] : 0;
        __syncthreads();
        s[tid] += v;
        __syncthreads();
    }
    int r = boff[blockIdx.x] + s[tid] - c;
    rowptr[g] = r;
    fill[g] = r;    // becomes scatter cursor
}

// ---------------- scatter edges into CSR (+ per-edge seg map) ----------------
__global__ __launch_bounds__(256) void k_scatter(const int* __restrict__ edge_index,
                                                 const int* __restrict__ edge_attr,
                                                 int* __restrict__ fill,
                                                 int* __restrict__ colidx,
                                                 int* __restrict__ esegG) {
    int e = blockIdx.x * 256 + threadIdx.x;
    if (e < EE) {
        int seg = edge_index[EE + e] * RR + edge_attr[e];
        int pos = atomicAdd(&fill[seg], 1);
        colidx[pos] = edge_index[e];   // src
        esegG[pos]  = seg;
    }
}

// ---------------- merged weight prep: fragment-tiled WT + W_ih bf16 + hGsum zero ----------------
__global__ __launch_bounds__(256) void k_wprep(const float* __restrict__ rel,
                                               const float* __restrict__ root,
                                               const float* __restrict__ w_ih,
                                               u16* __restrict__ WTt,
                                               u16* __restrict__ WTih,
                                               float* __restrict__ hGsum) {
    int idx = blockIdx.x * 256 + threadIdx.x;
    if (idx < 384 * H) WTih[idx] = f2b(w_ih[idx]);
    if (idx < BB * H) hGsum[idx] = 0.f;
    if (idx >= 3 * 147456) return;
    int li  = idx / 147456;
    int rem = idx - li * 147456;
    int tile = rem / 36864;
    int r2   = rem - tile * 36864;
    int ks   = r2 / 1024;
    int r3   = r2 - ks * 1024;
    int sub  = r3 >> 9;
    int r4   = r3 & 511;
    int lane = r4 >> 3, j = r4 & 7;
    int col = tile * 32 + sub * 16 + (lane & 15);
    int k   = ks * 32 + (lane >> 4) * 8 + j;
    float v;
    if (k < 1024) v = rel[(((size_t)li * RR + (k >> 7)) * H + (k & 127)) * H + col];
    else          v = root[((size_t)li * H + (k - 1024)) * H + col];
    WTt[idx] = f2b(v);
}

// ---------------- one RGCN layer: edge-parallel gather + bf16 MFMA GEMM + relu ----------------
// r13 gather (simple i+=4 loop — batching measured as a regression twice),
// coalesced fragment-tiled B, register double-buffered B-stream, fused L3 pool.
#define RGN 16           // nodes per block; grid = 512
#define EPRE 512

__global__ __launch_bounds__(256) void k_rgcn(const float* __restrict__ xin,
                                              float* __restrict__ xout,
                                              const u16* __restrict__ WTt,    // fragment-tiled
                                              const float* __restrict__ bias, // [H]
                                              const int* __restrict__ rowptr,
                                              const int* __restrict__ colidx,
                                              const int* __restrict__ esegG,
                                              float* __restrict__ hGsum) {   // null except L3
    __shared__ float Af[RGN][1160];        // 74.24 KB f32 staging (stride-padded)
    __shared__ int begs[RGN * RR + 1];
    __shared__ int eidx[EPRE];
    __shared__ int eseg[EPRE];
    u32* ab = (u32*)&Af[0][0];             // bf16-packed overlay, row stride 580 u32
    int tid = threadIdx.x, wv = tid >> 6, lane = tid & 63;
    int n0 = blockIdx.x * RGN, segbase = n0 * RR;

    if (tid <= RGN * RR) begs[tid] = rowptr[segbase + tid];
    for (int i = tid; i < RGN * 256; i += 256) {
        int row = i >> 8, q = i & 255;
        *(float4*)&Af[row][q * 4] = make_float4(0.f, 0.f, 0.f, 0.f);
    }
    __syncthreads();
    int E0 = begs[0], ne = begs[RGN * RR] - E0;
    for (int i = tid; i < ne && i < EPRE; i += 256) {
        eidx[i] = colidx[E0 + i];
        eseg[i] = esegG[E0 + i];
    }
    __syncthreads();

    // phase A: edge-parallel gather (wave = edge, lanes cover H via float2) — r13 form
    for (int i = wv; i < ne; i += 4) {
        int src, sl;
        if (i < EPRE) { src = eidx[i];        sl = eseg[i] - segbase; }
        else          { src = colidx[E0 + i]; sl = esegG[E0 + i] - segbase; }
        float2 v = ((const float2*)(xin + (size_t)src * H))[lane];
        float* dst = &Af[sl >> 3][((sl & 7) << 7) + 2 * lane];
        atomicAdd(dst, v.x);
        atomicAdd(dst + 1, v.y);
    }
    __syncthreads();

    // phase B: mean + root append, pack to bf16 pairs (held in regs across barrier)
    int rown = tid >> 4, sbase = tid & 15;
    u32 pk[36];
#pragma unroll
    for (int i = 0; i < 36; ++i) {
        int s = sbase + (i << 4);
        int k0 = s << 1;
        float v0, v1;
        if (k0 < 1024) {
            int r = k0 >> 7;
            int cnt = begs[rown * RR + r + 1] - begs[rown * RR + r];
            float inv = 1.f / fmaxf((float)cnt, 1.f);
            v0 = Af[rown][k0] * inv;
            v1 = Af[rown][k0 + 1] * inv;
        } else {
            const float* xr = xin + (size_t)(n0 + rown) * H + (k0 - 1024);
            v0 = xr[0];
            v1 = xr[1];
        }
        pk[i] = pk2(v0, v1);
    }
    __syncthreads();
#pragma unroll
    for (int i = 0; i < 36; ++i)
        ab[rown * 580 + sbase + (i << 4)] = pk[i];
    __syncthreads();

    // MFMA GEMM: wave = 32-col tile; 36 ksteps of 16x16x32 bf16, 2 n-subtiles.
    // B register-double-buffered: next kstep's loads issue before this kstep's MFMAs.
    int m = lane & 15, quad = lane >> 4;
    int colbase = wv * 32;
    const u32* aP = ab + m * 580 + quad * 4;
    const u32* bT = (const u32*)WTt + (size_t)wv * 36 * 512 + lane * 4;
    f32x4 acc0 = {0.f, 0.f, 0.f, 0.f}, acc1 = {0.f, 0.f, 0.f, 0.f};
    bf16x8 b0c = *(const bf16x8*)bT;
    bf16x8 b1c = *(const bf16x8*)(bT + 256);
    for (int ks = 0; ks < 36; ++ks) {
        bf16x8 b0n, b1n;
        if (ks < 35) {
            b0n = *(const bf16x8*)(bT + (ks + 1) * 512);
            b1n = *(const bf16x8*)(bT + (ks + 1) * 512 + 256);
        }
        bf16x8 a = *(const bf16x8*)(aP + ks * 16);
        acc0 = __builtin_amdgcn_mfma_f32_16x16x32_bf16(a, b0c, acc0, 0, 0, 0);
        acc1 = __builtin_amdgcn_mfma_f32_16x16x32_bf16(a, b1c, acc1, 0, 0, 0);
        b0c = b0n; b1c = b1n;
    }
    int c0 = colbase + m, c1 = c0 + 16;
    float bv0 = bias[c0], bv1 = bias[c1];
    float so0 = 0.f, so1 = 0.f;
#pragma unroll
    for (int rg = 0; rg < 4; ++rg) {
        int n = n0 + quad * 4 + rg;
        float o0 = fmaxf(acc0[rg] + bv0, 0.f);
        float o1 = fmaxf(acc1[rg] + bv1, 0.f);
        xout[(size_t)n * H + c0] = o0;
        xout[(size_t)n * H + c1] = o1;
        so0 += o0; so1 += o1;
    }
    if (hGsum) {      // fused mean-pool partial sums (layer 3 only)
        so0 += __shfl_xor(so0, 16, 64);
        so0 += __shfl_xor(so0, 32, 64);
        so1 += __shfl_xor(so1, 16, 64);
        so1 += __shfl_xor(so1, 32, 64);
        if (quad == 0) {
            int g = n0 >> 7;
            atomicAdd(&hGsum[g * H + c0], so0);
            atomicAdd(&hGsum[g * H + c1], so1);
        }
    }
}

// ---------------- action head (reads fused pool sums; writes divided hG) ----------------
__global__ __launch_bounds__(128) void k_pool_act(const float* __restrict__ hGsum,
                                                  const int* __restrict__ nodes_bs,
                                                  const float* __restrict__ linA_w,
                                                  const float* __restrict__ linA_b,
                                                  const float* __restrict__ linAf_w,
                                                  const float* __restrict__ linAf_b,
                                                  float* __restrict__ hG,
                                                  float* __restrict__ out) {
    __shared__ float hgs[H], t1[H];
    int b = blockIdx.x, h = threadIdx.x;
    float hg = hGsum[(size_t)b * H + h] / (float)nodes_bs[b];
    hG[(size_t)b * H + h] = hg;
    hgs[h] = hg;
    __syncthreads();
    float acc = linA_b[h];
    const float* wr = linA_w + (size_t)h * H;
    for (int k = 0; k < H; ++k) acc += wr[k] * hgs[k];
    t1[h] = fmaxf(acc, 0.f);
    __syncthreads();
    if (h < VA) {
        float a = linAf_b[h];
        const float* w2 = linAf_w + (size_t)h * H;
        for (int k = 0; k < H; ++k) a += w2[k] * t1[k];
        out[(size_t)b * VA + h] = a;
    }
}

// ---------------- sequence pooling -> SHIFTED GRU input igG ----------------
__global__ __launch_bounds__(256) void k_seqpool(const float* __restrict__ xf,
                                                 const float* __restrict__ seq,
                                                 const float* __restrict__ emb_actions,
                                                 const int* __restrict__ action_input,
                                                 float* __restrict__ igG) {
    __shared__ float xg[64][H];        // 32 KB
    __shared__ u16 lists[LL][64];      // 6 KB
    __shared__ int cnts[LL];
    int b = blockIdx.x, tid = threadIdx.x;
    int col = tid & 127, tg = tid >> 7;
    float acc[24];
#pragma unroll
    for (int m = 0; m < 24; ++m) acc[m] = 0.f;

    for (int chunk = 0; chunk < 2; ++chunk) {
        int i0 = b * NPG + chunk * 64;
        __syncthreads();
        if (tid < LL) cnts[tid] = 0;
        __syncthreads();
        for (int idx = tid; idx < 64 * H / 4; idx += 256)
            ((float4*)&xg[0][0])[idx] = ((const float4*)(xf + (size_t)i0 * H))[idx];
        for (int idx = tid; idx < 64 * LL; idx += 256) {
            int i = idx / LL, t = idx - i * LL;
            if (seq[(size_t)(i0 + i) * LL + t] != 0.f) {
                int p = atomicAdd(&cnts[t], 1);
                lists[t][p] = (u16)i;
            }
        }
        __syncthreads();
        for (int m = 0; m < 24; ++m) {
            int t = tg + 2 * m;
            int c = cnts[t];
            float a = acc[m];
            for (int p = 0; p < c; ++p) a += xg[lists[t][p]][col];
            acc[m] = a;
        }
    }
    if (tid < H)
        igG[((size_t)b * LL) * H + tid] = emb_actions[(size_t)action_input[b] * H + tid];
#pragma unroll
    for (int m = 0; m < 24; ++m) {
        int t = tg + 2 * m;
        if (t < LL - 1)
            igG[((size_t)b * LL + t + 1) * H + col] = acc[m];
    }
}

// ---------------- xw GEMM: xwG[3072][384] = igG @ W_ih^T + b_ih (bf16 out, MFMA) ----------------
__global__ __launch_bounds__(256) void k_xw(const float* __restrict__ igG,
                                            const u16* __restrict__ WTih,
                                            const float* __restrict__ b_ih,
                                            u16* __restrict__ xwG) {
    __shared__ u32 ab[16 * 68];        // 4.35 KB, stride 68
    int tid = threadIdx.x, wv = tid >> 6, lane = tid & 63;
    int n0 = blockIdx.x * 16;
    for (int s = tid; s < 16 * 64; s += 256) {
        int row = s >> 6, kp = s & 63;
        float2 v = *(const float2*)(igG + (size_t)(n0 + row) * H + 2 * kp);
        ab[row * 68 + kp] = pk2(v.x, v.y);
    }
    __syncthreads();
    int m = lane & 15, quad = lane >> 4;
    const u32* aP = ab + m * 68 + quad * 4;
    f32x4 acc[6];
#pragma unroll
    for (int i = 0; i < 6; ++i) acc[i] = (f32x4){0.f, 0.f, 0.f, 0.f};
#pragma unroll
    for (int ks = 0; ks < 4; ++ks) {
        bf16x8 a = *(const bf16x8*)(aP + ks * 16);
#pragma unroll
        for (int tc = 0; tc < 6; ++tc) {
            int colr = wv * 96 + tc * 16 + m;
            bf16x8 bfr = *(const bf16x8*)((const u32*)WTih + (size_t)colr * 64 + quad * 4 + ks * 16);
            acc[tc] = __builtin_amdgcn_mfma_f32_16x16x32_bf16(a, bfr, acc[tc], 0, 0, 0);
        }
    }
#pragma unroll
    for (int tc = 0; tc < 6; ++tc) {
        int c = wv * 96 + tc * 16 + m;
        float bv = b_ih[c];
#pragma unroll
        for (int rg = 0; rg < 4; ++rg) {
            int r = n0 + quad * 4 + rg;
            xwG[(size_t)r * 384 + c] = f2b(acc[tc][rg] + bv);
        }
    }
}

// ---------------- GRU: sequential steps only ----------------
__global__ __launch_bounds__(768) void k_gru(const u16* __restrict__ xwG,
                                             const float* __restrict__ hG,
                                             const float* __restrict__ w_hh,
                                             const float* __restrict__ b_hh,
                                             const int* __restrict__ len_seq,
                                             float* __restrict__ soutG) {
    __shared__ float xws[LL][3 * H];    // 73.7 KB
    __shared__ float hbuf[H];
    __shared__ float gh[3 * H];
    int b = blockIdx.x, tid = threadIdx.x;

    const u16* src = xwG + (size_t)b * LL * 384;
    float* xf = &xws[0][0];
    for (int idx = tid; idx < LL * 384; idx += 768) xf[idx] = b2f(src[idx]);
    if (tid < H) hbuf[tid] = hG[(size_t)b * H + tid];

    int j = tid >> 1, half = tid & 1;
    u32 wh[32];
    {
        const float* wp = w_hh + (size_t)j * H + 2 * half;   // elements 4k+2h, 4k+2h+1
#pragma unroll
        for (int k = 0; k < 32; ++k) wh[k] = pk2(wp[4 * k], wp[4 * k + 1]);
    }
    float bhh = b_hh[j];
    int ls = len_seq[b];
    __syncthreads();

    for (int t = 0; t < LL; ++t) {
        const float* hb = hbuf + 2 * half;
        float a = 0.f;
#pragma unroll
        for (int k = 0; k < 32; ++k) {
            float2 w = up2(wh[k]);
            float2 h2 = *(const float2*)&hb[4 * k];
            a += w.x * h2.x + w.y * h2.y;
        }
        a += __shfl_xor(a, 1, 64);
        if (half == 0) gh[j] = a + bhh;
        __syncthreads();
        if (tid < H) {
            float rg = 1.f / (1.f + __expf(-(xws[t][tid] + gh[tid])));
            float zg = 1.f / (1.f + __expf(-(xws[t][tid + H] + gh[tid + H])));
            float ng = tanhf(xws[t][tid + 2 * H] + rg * gh[tid + 2 * H]);
            float hnew = (1.f - zg) * ng + zg * hbuf[tid];
            hbuf[tid] = hnew;
            soutG[((size_t)b * LL + t) * H + tid] = (t < ls) ? hnew : 0.f;
        }
        __syncthreads();
    }
}

// ---------------- A2[row,:] = W1a @ sout[row]  (rows = b*48+t), f32 out ----------------
__global__ __launch_bounds__(256) void k_a2(const float* __restrict__ soutG,
                                            const float* __restrict__ linN_w,
                                            float* __restrict__ A2) {
    __shared__ float wb[32][130];
    __shared__ float xl[16][H];
    int tid = threadIdx.x;
    int n0 = blockIdx.x * 16;
    for (int idx = tid; idx < 16 * H; idx += 256)
        xl[idx >> 7][idx & 127] = soutG[(size_t)n0 * H + idx];
    int col = tid & 127, g = tid >> 7;
    float acc[8] = {0.f, 0.f, 0.f, 0.f, 0.f, 0.f, 0.f, 0.f};
    for (int c = 0; c < 4; ++c) {
        int k0 = c * 32;
        __syncthreads();
        for (int idx = tid; idx < 32 * H; idx += 256) {
            int r = idx >> 5, kk = idx & 31;
            wb[kk][r] = linN_w[(size_t)r * (2 * H) + k0 + kk];
        }
        __syncthreads();
#pragma unroll
        for (int kk = 0; kk < 32; ++kk) {
            float w = wb[kk][col];
#pragma unroll
            for (int j = 0; j < 8; ++j) acc[j] += xl[g * 8 + j][k0 + kk] * w;
        }
    }
#pragma unroll
    for (int j = 0; j < 8; ++j)
        A2[(size_t)(n0 + g * 8 + j) * H + col] = acc[j];
}

// ---------------- Bx[n,:] = W1b @ x[n] + linN_b (bf16 out) ----------------
__global__ __launch_bounds__(256) void k_bx(const float* __restrict__ xf,
                                            const float* __restrict__ linN_w,
                                            const float* __restrict__ linN_b,
                                            u16* __restrict__ BxU) {
    __shared__ float wb[32][130];
    __shared__ float xl[16][H];
    int tid = threadIdx.x;
    int n0 = blockIdx.x * 16;
    for (int idx = tid; idx < 16 * H; idx += 256)
        xl[idx >> 7][idx & 127] = xf[(size_t)n0 * H + idx];
    int col = tid & 127, g = tid >> 7;
    float bv = linN_b[col];
    float acc[8] = {bv, bv, bv, bv, bv, bv, bv, bv};
    for (int c = 0; c < 4; ++c) {
        int k0 = c * 32;
        __syncthreads();
        for (int idx = tid; idx < 32 * H; idx += 256) {
            int r = idx >> 5, kk = idx & 31;
            wb[kk][r] = linN_w[(size_t)r * (2 * H) + H + k0 + kk];
        }
        __syncthreads();
#pragma unroll
        for (int kk = 0; kk < 32; ++kk) {
            float w = wb[kk][col];
#pragma unroll
            for (int j = 0; j < 8; ++j) acc[j] += xl[g * 8 + j][k0 + kk] * w;
        }
    }
#pragma unroll
    for (int j = 0; j < 8; ++j)
        BxU[(size_t)(n0 + g * 8 + j) * H + col] = f2b(acc[j]);
}

// ---------------- logits[n][t] = sum_k w2[k]*relu(A2[t][k]+Bx[n][k]) ----------------
__global__ __launch_bounds__(256) void k_logits(const float* __restrict__ A2,
                                                const u16* __restrict__ BxU,
                                                const float* __restrict__ linNf_w,
                                                float* __restrict__ logits) {
    __shared__ float a2s[LL][130];
    __shared__ float bxs[16][130];
    __shared__ float w2s[H];
    int tid = threadIdx.x;
    int g = blockIdx.x >> 3, tile = blockIdx.x & 7;
    int n0g = g * NPG + tile * 16;

    for (int i2 = tid; i2 < LL * 64; i2 += 256) {
        int r = i2 >> 6, c2 = i2 & 63;
        *(float2*)&a2s[r][2 * c2] = *(const float2*)(A2 + ((size_t)g * LL + r) * H + 2 * c2);
    }
    for (int iu = tid; iu < 16 * 64; iu += 256) {
        int r = iu >> 6, c = iu & 63;
        float2 v = up2(((const u32*)BxU)[(size_t)(n0g + r) * 64 + c]);
        *(float2*)&bxs[r][2 * c] = v;
    }
    if (tid < H) w2s[tid] = linNf_w[tid];
    __syncthreads();

    int n = tid & 15, tt = tid >> 4;
#pragma unroll
    for (int pass = 0; pass < 3; ++pass) {
        int t = tt + 16 * pass;
        float acc = 0.f;
#pragma unroll
        for (int kp = 0; kp < 64; ++kp) {
            float2 a2 = *(const float2*)&a2s[t][2 * kp];
            float2 bx = *(const float2*)&bxs[n][2 * kp];
            float2 w  = *(const float2*)&w2s[2 * kp];
            acc += w.x * fmaxf(a2.x + bx.x, 0.f) + w.y * fmaxf(a2.y + bx.y, 0.f);
        }
        logits[(size_t)(n0g + n) * LL + t] = acc;
    }
}

// ---------------- per-(graph,t) softmax over nodes; write output ----------------
__global__ __launch_bounds__(256) void k_softmax(const float* __restrict__ logits,
                                                 float* __restrict__ out) {
    __shared__ float lg[NPG][LL + 1];
    __shared__ float pm[4][LL], ps[4][LL];
    __shared__ float mv[LL], inv[LL];
    int b = blockIdx.x, tid = threadIdx.x;
    int n0 = b * NPG;
    for (int idx = tid; idx < NPG * LL; idx += 256) {
        int n = idx / LL, t = idx - n * LL;
        lg[n][t] = logits[(size_t)n0 * LL + idx];
    }
    __syncthreads();
    int t = tid & 63, seg = tid >> 6;
    if (t < LL) {
        float m = -1e30f;
        int nb = seg * 32;
        for (int n = nb; n < nb + 32; ++n) m = fmaxf(m, lg[n][t]);
        pm[seg][t] = m;
    }
    __syncthreads();
    if (tid < LL)
        mv[tid] = fmaxf(fmaxf(pm[0][tid], pm[1][tid]), fmaxf(pm[2][tid], pm[3][tid]));
    __syncthreads();
    if (t < LL) {
        float m = mv[t], s = 0.f;
        int nb = seg * 32;
        for (int n = nb; n < nb + 32; ++n) {
            float e = __expf(lg[n][t] - m);
            lg[n][t] = e;
            s += e;
        }
        ps[seg][t] = s;
    }
    __syncthreads();
    if (tid < LL)
        inv[tid] = 1.f / (ps[0][tid] + ps[1][tid] + ps[2][tid] + ps[3][tid]);
    __syncthreads();
    for (int idx = tid; idx < NPG * LL; idx += 256) {
        int n = idx / LL, tc = idx - n * LL;
        out[(size_t)BB * VA + (size_t)n0 * LL + idx] = lg[n][tc] * inv[tc];
    }
}

// ---------------- launch ----------------
extern "C" void kernel_launch(void* const* d_in, const int* in_sizes, int n_in,
                              void* d_out, int out_size, void* d_ws, size_t ws_size,
                              hipStream_t stream) {
    (void)in_sizes; (void)n_in; (void)out_size; (void)ws_size;
    const int*   nodeTypes    = (const int*)d_in[0];
    const int*   edge_index   = (const int*)d_in[1];
    const int*   edge_attr    = (const int*)d_in[2];
    const int*   nodes_bs     = (const int*)d_in[4];
    const int*   len_seq      = (const int*)d_in[5];
    const float* seq_in       = (const float*)d_in[6];
    const int*   action_input = (const int*)d_in[7];
    const float* emb_nodes    = (const float*)d_in[8];
    const float* emb_actions  = (const float*)d_in[9];
    const float* rgcn_rel     = (const float*)d_in[10];
    const float* rgcn_root    = (const float*)d_in[11];
    const float* rgcn_bias    = (const float*)d_in[12];
    const float* gru_w_ih     = (const float*)d_in[13];
    const float* gru_w_hh     = (const float*)d_in[14];
    const float* gru_b_ih     = (const float*)d_in[15];
    const float* gru_b_hh     = (const float*)d_in[16];
    const float* linA_w       = (const float*)d_in[17];
    const float* linA_b       = (const float*)d_in[18];
    const float* linAf_w      = (const float*)d_in[19];
    const float* linAf_b      = (const float*)d_in[20];
    const float* linN_w       = (const float*)d_in[21];
    const float* linN_b       = (const float*)d_in[22];
    const float* linNf_w      = (const float*)d_in[23];
    // linNf_b cancels in the softmax

    char* w = (char*)d_ws;
    float* x0      = (float*)(w + 0);          // [0,4MB) emb ping; dead after rgcn L3
    u16*   xwG     = (u16*)  (w + 0);          //   overlay (after L3): [0, 2,359,296)
    float* logitsW = (float*)(w + 0);          //   overlay (after k_gru): [0, 1,572,864)
    float* soutG   = (float*)(w + 2359296);    //   overlay (after L3): [.., 3,932,160)
    float* x1      = (float*)(w + 4194304);    // [4MB,8MB) final x f32 (live to end)
    float* igG     = (float*)(w + 8388608);    // [8MB, 9,961,472) shifted GRU input
    float* A2      = (float*)(w + 8388608);    //   overlay (igG dead before k_a2)
    u16*   BxU     = (u16*)  (w + 9961472);    // [9,961,472, 12,058,624)
    int*   bsum    = (int*)  (w + 9961472);    //   overlay on BxU (dead until k_bx)
    int*   boff    = (int*)  (w + 9962496);    //   overlay on BxU + 1 KB
    float* hGsum   = (float*)(w + 9969664);    //   overlay on BxU + 8 KB (dead by k_bx)
    int*   rowptr  = (int*)  (w + 11567104);   // dead after rgcn L3
    int*   fill    = (int*)  (w + 11829760);   // dead after scatter
    u16*   WTih    = (u16*)  (w + 11829760);   //   overlay fill; dead after k_xw
    float* hG      = (float*)(w + 12058624);   // 32 KB
    int*   colidx  = (int*)  (w + 12091904);   // dead after rgcn L3
    int*   esegG   = (int*)  (w + 12354048);   // dead after rgcn L3
    u16*   WT      = (u16*)  (w + 12616192);   // rgcn weights bf16 (tiled), 884,736 B

    float* out_f = (float*)d_out;

    k_init<<<dim3(4096), dim3(256), 0, stream>>>(nodeTypes, emb_nodes, x0, fill);
    k_hist<<<dim3(256), dim3(256), 0, stream>>>(edge_index, edge_attr, fill);
    k_scan1<<<dim3(256), dim3(256), 0, stream>>>(fill, bsum);
    k_scan2<<<dim3(1), dim3(256), 0, stream>>>(bsum, boff, rowptr);
    k_scan3<<<dim3(256), dim3(256), 0, stream>>>(boff, fill, rowptr);
    k_scatter<<<dim3(256), dim3(256), 0, stream>>>(edge_index, edge_attr, fill, colidx, esegG);
    k_wprep<<<dim3(1728), dim3(256), 0, stream>>>(rgcn_rel, rgcn_root, gru_w_ih,
                                                  WT, WTih, hGsum);

    const int rg_grid = NN / RGN;   // 512
    k_rgcn<<<dim3(rg_grid), dim3(256), 0, stream>>>(x0, x1,
        WT + 0 * 147456, rgcn_bias + 0 * H, rowptr, colidx, esegG, nullptr);
    k_rgcn<<<dim3(rg_grid), dim3(256), 0, stream>>>(x1, x0,
        WT + 1 * 147456, rgcn_bias + 1 * H, rowptr, colidx, esegG, nullptr);
    k_rgcn<<<dim3(rg_grid), dim3(256), 0, stream>>>(x0, x1,
        WT + 2 * 147456, rgcn_bias + 2 * H, rowptr, colidx, esegG, hGsum);
    // x_final = x1 (x0 region free from here)

    k_pool_act<<<dim3(BB), dim3(128), 0, stream>>>(hGsum, nodes_bs, linA_w, linA_b,
                                                   linAf_w, linAf_b, hG, out_f);
    k_seqpool<<<dim3(BB), dim3(256), 0, stream>>>(x1, seq_in, emb_actions, action_input, igG);
    k_xw<<<dim3(BB * LL / 16), dim3(256), 0, stream>>>(igG, WTih, gru_b_ih, xwG);
    k_gru<<<dim3(BB), dim3(768), 0, stream>>>(xwG, hG, gru_w_hh, gru_b_hh, len_seq, soutG);
    k_a2<<<dim3(BB * LL / 16), dim3(256), 0, stream>>>(soutG, linN_w, A2);
    k_bx<<<dim3(NN / 16), dim3(256), 0, stream>>>(x1, linN_w, linN_b, BxU);
    k_logits<<<dim3(BB * 8), dim3(256), 0, stream>>>(A2, BxU, linNf_w, logitsW);
    k_softmax<<<dim3(BB), dim3(256), 0, stream>>>(logitsW, out_f);
}

// Round 16
// 372.990 us; speedup vs baseline: 1.3179x; 1.2532x over previous
//
#include <hip/hip_runtime.h>
#include <hip/hip_bf16.h>

#define H   128
#define RR  8
#define NN  8192
#define BB  64
#define LL  48
#define EE  65536
#define NPG 128          // nodes per graph (N/B)
#define VA  64
#define NSEG (NN*RR)     // 65536

typedef unsigned short u16;
typedef unsigned int   u32;

__device__ __forceinline__ float b2f(u16 u) {
    union { u32 i; float f; } v; v.i = ((u32)u) << 16; return v.f;
}
__device__ __forceinline__ u16 f2b(float f) {
    union { float f; u32 i; } v; v.f = f;
    u32 x = v.i;
    return (u16)((x + 0x7fffu + ((x >> 16) & 1u)) >> 16);
}
__device__ __forceinline__ float2 up2(u32 p) {
    union { u32 i; float f; } a, b;
    a.i = p << 16; b.i = p & 0xffff0000u;
    return make_float2(a.f, b.f);
}
__device__ __forceinline__ u32 pk2(float a, float b) {
    return ((u32)f2b(b) << 16) | (u32)f2b(a);
}

typedef __attribute__((ext_vector_type(8))) short bf16x8;
typedef __attribute__((ext_vector_type(4))) float f32x4;

// ---------------- init: zero seg counters + embed nodes (f32 out) ----------------
__global__ __launch_bounds__(256) void k_init(const int* __restrict__ nodeTypes,
                                              const float* __restrict__ emb_nodes,
                                              float* __restrict__ x0,
                                              int* __restrict__ fill) {
    int idx = blockIdx.x * 256 + threadIdx.x;
    if (idx < NSEG) fill[idx] = 0;
    if (idx < NN * H) {
        int n = idx >> 7, h = idx & (H - 1);
        x0[idx] = emb_nodes[(size_t)nodeTypes[n] * H + h];
    }
}

// ---------------- histogram of (dst,rel) segments ----------------
__global__ __launch_bounds__(256) void k_hist(const int* __restrict__ edge_index,
                                              const int* __restrict__ edge_attr,
                                              int* __restrict__ fill) {
    int e = blockIdx.x * 256 + threadIdx.x;
    if (e < EE) {
        int seg = edge_index[EE + e] * RR + edge_attr[e];
        atomicAdd(&fill[seg], 1);
    }
}

// ---------------- 3-stage parallel exclusive scan over 65536 counts ----------------
__global__ __launch_bounds__(256) void k_scan1(const int* __restrict__ fill,
                                               int* __restrict__ bsum) {
    __shared__ int red[4];
    int tid = threadIdx.x, lane = tid & 63, wv = tid >> 6;
    int v = fill[blockIdx.x * 256 + tid];
#pragma unroll
    for (int off = 32; off >= 1; off >>= 1) v += __shfl_down(v, off, 64);
    if (lane == 0) red[wv] = v;
    __syncthreads();
    if (tid == 0) bsum[blockIdx.x] = red[0] + red[1] + red[2] + red[3];
}

__global__ __launch_bounds__(256) void k_scan2(const int* __restrict__ bsum,
                                               int* __restrict__ boff,
                                               int* __restrict__ rowptr) {
    __shared__ int s[256];
    int tid = threadIdx.x;
    int v0 = bsum[tid];
    s[tid] = v0;
    __syncthreads();
    for (int off = 1; off < 256; off <<= 1) {
        int v = (tid >= off) ? s[tid - off] : 0;
        __syncthreads();
        s[tid] += v;
        __syncthreads();
    }
    boff[tid] = s[tid] - v0;           // exclusive
    if (tid == 255) rowptr[NSEG] = s[255];
}

__global__ __launch_bounds__(256) void k_scan3(const int* __restrict__ boff,
                                               int* __restrict__ fill,
                                               int* __restrict__ rowptr) {
    __shared__ int s[256];
    int tid = threadIdx.x;
    int g = blockIdx.x * 256 + tid;
    int c = fill[g];
    s[tid] = c;
    __syncthreads();
    for (int off = 1; off < 256; off <<= 1) {
        int v = (tid >= off) ? s[tid - off] : 0;
        __syncthreads();
        s[tid] += v;
        __syncthreads();
    }
    int r = boff[blockIdx.x] + s[tid] - c;
    rowptr[g] = r;
    fill[g] = r;    // becomes scatter cursor
}

// ---------------- scatter edges into CSR ----------------
__global__ __launch_bounds__(256) void k_scatter(const int* __restrict__ edge_index,
                                                 const int* __restrict__ edge_attr,
                                                 int* __restrict__ fill,
                                                 int* __restrict__ colidx) {
    int e = blockIdx.x * 256 + threadIdx.x;
    if (e < EE) {
        int seg = edge_index[EE + e] * RR + edge_attr[e];
        int pos = atomicAdd(&fill[seg], 1);
        colidx[pos] = edge_index[e];   // src
    }
}

// ---------------- merged weight prep: fragment-tiled WT + W_ih bf16 + hGsum zero ----------------
__global__ __launch_bounds__(256) void k_wprep(const float* __restrict__ rel,
                                               const float* __restrict__ root,
                                               const float* __restrict__ w_ih,
                                               u16* __restrict__ WTt,
                                               u16* __restrict__ WTih,
                                               float* __restrict__ hGsum) {
    int idx = blockIdx.x * 256 + threadIdx.x;
    if (idx < 384 * H) WTih[idx] = f2b(w_ih[idx]);
    if (idx < BB * H) hGsum[idx] = 0.f;
    if (idx >= 3 * 147456) return;
    int li  = idx / 147456;
    int rem = idx - li * 147456;
    int tile = rem / 36864;
    int r2   = rem - tile * 36864;
    int ks   = r2 / 1024;
    int r3   = r2 - ks * 1024;
    int sub  = r3 >> 9;
    int r4   = r3 & 511;
    int lane = r4 >> 3, j = r4 & 7;
    int col = tile * 32 + sub * 16 + (lane & 15);
    int k   = ks * 32 + (lane >> 4) * 8 + j;
    float v;
    if (k < 1024) v = rel[(((size_t)li * RR + (k >> 7)) * H + (k & 127)) * H + col];
    else          v = root[((size_t)li * H + (k - 1024)) * H + col];
    WTt[idx] = f2b(v);
}

// ---------------- one RGCN layer: segment-parallel register gather + bf16 MFMA GEMM ----------------
// Wave = segment (avg degree 1): register accumulate, pack bf16 straight into ab.
// No atomics, no f32 staging -> LDS ~40 KB -> 4 blocks/CU, all 512 blocks co-resident.
#define RGN 16           // nodes per block; grid = 512
#define EPRE 512

__global__ __launch_bounds__(256) void k_rgcn(const float* __restrict__ xin,
                                              float* __restrict__ xout,
                                              const u16* __restrict__ WTt,    // fragment-tiled
                                              const float* __restrict__ bias, // [H]
                                              const int* __restrict__ rowptr,
                                              const int* __restrict__ colidx,
                                              float* __restrict__ hGsum) {   // null except L3
    __shared__ u32 ab[RGN * 580];          // 37.1 KB bf16-packed A (row stride 580)
    __shared__ int begs[RGN * RR + 1];
    __shared__ int eidx[EPRE];
    int tid = threadIdx.x, wv = tid >> 6, lane = tid & 63;
    int n0 = blockIdx.x * RGN, segbase = n0 * RR;

    if (tid <= RGN * RR) begs[tid] = rowptr[segbase + tid];
    __syncthreads();
    int E0 = begs[0], ne = begs[RGN * RR] - E0;
    for (int i = tid; i < ne && i < EPRE; i += 256) eidx[i] = colidx[E0 + i];
    __syncthreads();

    // phase A: wave per segment; lanes cover H via float2; mean in registers; packed write
    for (int s = wv; s < RGN * RR; s += 4) {
        int beg = begs[s], end = begs[s + 1];
        float a0 = 0.f, a1 = 0.f;
        for (int e = beg; e < end; ++e) {
            int off = e - E0;
            int src = (off < EPRE) ? eidx[off] : colidx[e];
            float2 v = ((const float2*)(xin + (size_t)src * H))[lane];
            a0 += v.x; a1 += v.y;
        }
        float inv = 1.f / fmaxf((float)(end - beg), 1.f);
        ab[(s >> 3) * 580 + ((s & 7) << 6) + lane] = pk2(a0 * inv, a1 * inv);
    }
    // root block: k-pair slots 512..575
    for (int i = wv; i < RGN; i += 4) {
        const float* xr = xin + (size_t)(n0 + i) * H + 2 * lane;
        ab[i * 580 + 512 + lane] = pk2(xr[0], xr[1]);
    }
    __syncthreads();

    // MFMA GEMM: wave = 32-col tile; 36 ksteps of 16x16x32 bf16, 2 n-subtiles (r15 form)
    int m = lane & 15, quad = lane >> 4;
    int colbase = wv * 32;
    const u32* aP = ab + m * 580 + quad * 4;
    const u32* bT = (const u32*)WTt + (size_t)wv * 36 * 512 + lane * 4;
    f32x4 acc0 = {0.f, 0.f, 0.f, 0.f}, acc1 = {0.f, 0.f, 0.f, 0.f};
    bf16x8 b0c = *(const bf16x8*)bT;
    bf16x8 b1c = *(const bf16x8*)(bT + 256);
    for (int ks = 0; ks < 36; ++ks) {
        bf16x8 b0n, b1n;
        if (ks < 35) {
            b0n = *(const bf16x8*)(bT + (ks + 1) * 512);
            b1n = *(const bf16x8*)(bT + (ks + 1) * 512 + 256);
        }
        bf16x8 a = *(const bf16x8*)(aP + ks * 16);
        acc0 = __builtin_amdgcn_mfma_f32_16x16x32_bf16(a, b0c, acc0, 0, 0, 0);
        acc1 = __builtin_amdgcn_mfma_f32_16x16x32_bf16(a, b1c, acc1, 0, 0, 0);
        b0c = b0n; b1c = b1n;
    }
    int c0 = colbase + m, c1 = c0 + 16;
    float bv0 = bias[c0], bv1 = bias[c1];
    float so0 = 0.f, so1 = 0.f;
#pragma unroll
    for (int rg = 0; rg < 4; ++rg) {
        int n = n0 + quad * 4 + rg;
        float o0 = fmaxf(acc0[rg] + bv0, 0.f);
        float o1 = fmaxf(acc1[rg] + bv1, 0.f);
        xout[(size_t)n * H + c0] = o0;
        xout[(size_t)n * H + c1] = o1;
        so0 += o0; so1 += o1;
    }
    if (hGsum) {      // fused mean-pool partial sums (layer 3 only)
        so0 += __shfl_xor(so0, 16, 64);
        so0 += __shfl_xor(so0, 32, 64);
        so1 += __shfl_xor(so1, 16, 64);
        so1 += __shfl_xor(so1, 32, 64);
        if (quad == 0) {
            int g = n0 >> 7;
            atomicAdd(&hGsum[g * H + c0], so0);
            atomicAdd(&hGsum[g * H + c1], so1);
        }
    }
}

// ---------------- action head (reads fused pool sums; writes divided hG) ----------------
__global__ __launch_bounds__(128) void k_pool_act(const float* __restrict__ hGsum,
                                                  const int* __restrict__ nodes_bs,
                                                  const float* __restrict__ linA_w,
                                                  const float* __restrict__ linA_b,
                                                  const float* __restrict__ linAf_w,
                                                  const float* __restrict__ linAf_b,
                                                  float* __restrict__ hG,
                                                  float* __restrict__ out) {
    __shared__ float hgs[H], t1[H];
    int b = blockIdx.x, h = threadIdx.x;
    float hg = hGsum[(size_t)b * H + h] / (float)nodes_bs[b];
    hG[(size_t)b * H + h] = hg;
    hgs[h] = hg;
    __syncthreads();
    float acc = linA_b[h];
    const float* wr = linA_w + (size_t)h * H;
    for (int k = 0; k < H; ++k) acc += wr[k] * hgs[k];
    t1[h] = fmaxf(acc, 0.f);
    __syncthreads();
    if (h < VA) {
        float a = linAf_b[h];
        const float* w2 = linAf_w + (size_t)h * H;
        for (int k = 0; k < H; ++k) a += w2[k] * t1[k];
        out[(size_t)b * VA + h] = a;
    }
}

// ---------------- sequence pooling -> SHIFTED GRU input igG ----------------
__global__ __launch_bounds__(256) void k_seqpool(const float* __restrict__ xf,
                                                 const float* __restrict__ seq,
                                                 const float* __restrict__ emb_actions,
                                                 const int* __restrict__ action_input,
                                                 float* __restrict__ igG) {
    __shared__ float xg[64][H];        // 32 KB
    __shared__ u16 lists[LL][64];      // 6 KB
    __shared__ int cnts[LL];
    int b = blockIdx.x, tid = threadIdx.x;
    int col = tid & 127, tg = tid >> 7;
    float acc[24];
#pragma unroll
    for (int m = 0; m < 24; ++m) acc[m] = 0.f;

    for (int chunk = 0; chunk < 2; ++chunk) {
        int i0 = b * NPG + chunk * 64;
        __syncthreads();
        if (tid < LL) cnts[tid] = 0;
        __syncthreads();
        for (int idx = tid; idx < 64 * H / 4; idx += 256)
            ((float4*)&xg[0][0])[idx] = ((const float4*)(xf + (size_t)i0 * H))[idx];
        for (int idx = tid; idx < 64 * LL; idx += 256) {
            int i = idx / LL, t = idx - i * LL;
            if (seq[(size_t)(i0 + i) * LL + t] != 0.f) {
                int p = atomicAdd(&cnts[t], 1);
                lists[t][p] = (u16)i;
            }
        }
        __syncthreads();
        for (int m = 0; m < 24; ++m) {
            int t = tg + 2 * m;
            int c = cnts[t];
            float a = acc[m];
            for (int p = 0; p < c; ++p) a += xg[lists[t][p]][col];
            acc[m] = a;
        }
    }
    if (tid < H)
        igG[((size_t)b * LL) * H + tid] = emb_actions[(size_t)action_input[b] * H + tid];
#pragma unroll
    for (int m = 0; m < 24; ++m) {
        int t = tg + 2 * m;
        if (t < LL - 1)
            igG[((size_t)b * LL + t + 1) * H + col] = acc[m];
    }
}

// ---------------- xw GEMM: xwG[3072][384] = igG @ W_ih^T + b_ih (bf16 out, MFMA) ----------------
__global__ __launch_bounds__(256) void k_xw(const float* __restrict__ igG,
                                            const u16* __restrict__ WTih,
                                            const float* __restrict__ b_ih,
                                            u16* __restrict__ xwG) {
    __shared__ u32 ab[16 * 68];        // 4.35 KB, stride 68
    int tid = threadIdx.x, wv = tid >> 6, lane = tid & 63;
    int n0 = blockIdx.x * 16;
    for (int s = tid; s < 16 * 64; s += 256) {
        int row = s >> 6, kp = s & 63;
        float2 v = *(const float2*)(igG + (size_t)(n0 + row) * H + 2 * kp);
        ab[row * 68 + kp] = pk2(v.x, v.y);
    }
    __syncthreads();
    int m = lane & 15, quad = lane >> 4;
    const u32* aP = ab + m * 68 + quad * 4;
    f32x4 acc[6];
#pragma unroll
    for (int i = 0; i < 6; ++i) acc[i] = (f32x4){0.f, 0.f, 0.f, 0.f};
#pragma unroll
    for (int ks = 0; ks < 4; ++ks) {
        bf16x8 a = *(const bf16x8*)(aP + ks * 16);
#pragma unroll
        for (int tc = 0; tc < 6; ++tc) {
            int colr = wv * 96 + tc * 16 + m;
            bf16x8 bfr = *(const bf16x8*)((const u32*)WTih + (size_t)colr * 64 + quad * 4 + ks * 16);
            acc[tc] = __builtin_amdgcn_mfma_f32_16x16x32_bf16(a, bfr, acc[tc], 0, 0, 0);
        }
    }
#pragma unroll
    for (int tc = 0; tc < 6; ++tc) {
        int c = wv * 96 + tc * 16 + m;
        float bv = b_ih[c];
#pragma unroll
        for (int rg = 0; rg < 4; ++rg) {
            int r = n0 + quad * 4 + rg;
            xwG[(size_t)r * 384 + c] = f2b(acc[tc][rg] + bv);
        }
    }
}

// ---------------- GRU: sequential steps only ----------------
__global__ __launch_bounds__(768) void k_gru(const u16* __restrict__ xwG,
                                             const float* __restrict__ hG,
                                             const float* __restrict__ w_hh,
                                             const float* __restrict__ b_hh,
                                             const int* __restrict__ len_seq,
                                             float* __restrict__ soutG) {
    __shared__ float xws[LL][3 * H];    // 73.7 KB
    __shared__ float hbuf[H];
    __shared__ float gh[3 * H];
    int b = blockIdx.x, tid = threadIdx.x;

    const u16* src = xwG + (size_t)b * LL * 384;
    float* xf = &xws[0][0];
    for (int idx = tid; idx < LL * 384; idx += 768) xf[idx] = b2f(src[idx]);
    if (tid < H) hbuf[tid] = hG[(size_t)b * H + tid];

    int j = tid >> 1, half = tid & 1;
    u32 wh[32];
    {
        const float* wp = w_hh + (size_t)j * H + 2 * half;   // elements 4k+2h, 4k+2h+1
#pragma unroll
        for (int k = 0; k < 32; ++k) wh[k] = pk2(wp[4 * k], wp[4 * k + 1]);
    }
    float bhh = b_hh[j];
    int ls = len_seq[b];
    __syncthreads();

    for (int t = 0; t < LL; ++t) {
        const float* hb = hbuf + 2 * half;
        float a = 0.f;
#pragma unroll
        for (int k = 0; k < 32; ++k) {
            float2 w = up2(wh[k]);
            float2 h2 = *(const float2*)&hb[4 * k];
            a += w.x * h2.x + w.y * h2.y;
        }
        a += __shfl_xor(a, 1, 64);
        if (half == 0) gh[j] = a + bhh;
        __syncthreads();
        if (tid < H) {
            float rg = 1.f / (1.f + __expf(-(xws[t][tid] + gh[tid])));
            float zg = 1.f / (1.f + __expf(-(xws[t][tid + H] + gh[tid + H])));
            float ng = tanhf(xws[t][tid + 2 * H] + rg * gh[tid + 2 * H]);
            float hnew = (1.f - zg) * ng + zg * hbuf[tid];
            hbuf[tid] = hnew;
            soutG[((size_t)b * LL + t) * H + tid] = (t < ls) ? hnew : 0.f;
        }
        __syncthreads();
    }
}

// ---------------- A2[row,:] = W1a @ sout[row]  (rows = b*48+t), f32 out ----------------
__global__ __launch_bounds__(256) void k_a2(const float* __restrict__ soutG,
                                            const float* __restrict__ linN_w,
                                            float* __restrict__ A2) {
    __shared__ float wb[32][130];
    __shared__ float xl[16][H];
    int tid = threadIdx.x;
    int n0 = blockIdx.x * 16;
    for (int idx = tid; idx < 16 * H; idx += 256)
        xl[idx >> 7][idx & 127] = soutG[(size_t)n0 * H + idx];
    int col = tid & 127, g = tid >> 7;
    float acc[8] = {0.f, 0.f, 0.f, 0.f, 0.f, 0.f, 0.f, 0.f};
    for (int c = 0; c < 4; ++c) {
        int k0 = c * 32;
        __syncthreads();
        for (int idx = tid; idx < 32 * H; idx += 256) {
            int r = idx >> 5, kk = idx & 31;
            wb[kk][r] = linN_w[(size_t)r * (2 * H) + k0 + kk];
        }
        __syncthreads();
#pragma unroll
        for (int kk = 0; kk < 32; ++kk) {
            float w = wb[kk][col];
#pragma unroll
            for (int j = 0; j < 8; ++j) acc[j] += xl[g * 8 + j][k0 + kk] * w;
        }
    }
#pragma unroll
    for (int j = 0; j < 8; ++j)
        A2[(size_t)(n0 + g * 8 + j) * H + col] = acc[j];
}

// ---------------- Bx[n,:] = W1b @ x[n] + linN_b (bf16 out) ----------------
__global__ __launch_bounds__(256) void k_bx(const float* __restrict__ xf,
                                            const float* __restrict__ linN_w,
                                            const float* __restrict__ linN_b,
                                            u16* __restrict__ BxU) {
    __shared__ float wb[32][130];
    __shared__ float xl[16][H];
    int tid = threadIdx.x;
    int n0 = blockIdx.x * 16;
    for (int idx = tid; idx < 16 * H; idx += 256)
        xl[idx >> 7][idx & 127] = xf[(size_t)n0 * H + idx];
    int col = tid & 127, g = tid >> 7;
    float bv = linN_b[col];
    float acc[8] = {bv, bv, bv, bv, bv, bv, bv, bv};
    for (int c = 0; c < 4; ++c) {
        int k0 = c * 32;
        __syncthreads();
        for (int idx = tid; idx < 32 * H; idx += 256) {
            int r = idx >> 5, kk = idx & 31;
            wb[kk][r] = linN_w[(size_t)r * (2 * H) + H + k0 + kk];
        }
        __syncthreads();
#pragma unroll
        for (int kk = 0; kk < 32; ++kk) {
            float w = wb[kk][col];
#pragma unroll
            for (int j = 0; j < 8; ++j) acc[j] += xl[g * 8 + j][k0 + kk] * w;
        }
    }
#pragma unroll
    for (int j = 0; j < 8; ++j)
        BxU[(size_t)(n0 + g * 8 + j) * H + col] = f2b(acc[j]);
}

// ---------------- logits[n][t] = sum_k w2[k]*relu(A2[t][k]+Bx[n][k]) ----------------
__global__ __launch_bounds__(256) void k_logits(const float* __restrict__ A2,
                                                const u16* __restrict__ BxU,
                                                const float* __restrict__ linNf_w,
                                                float* __restrict__ logits) {
    __shared__ float a2s[LL][130];
    __shared__ float bxs[16][130];
    __shared__ float w2s[H];
    int tid = threadIdx.x;
    int g = blockIdx.x >> 3, tile = blockIdx.x & 7;
    int n0g = g * NPG + tile * 16;

    for (int i2 = tid; i2 < LL * 64; i2 += 256) {
        int r = i2 >> 6, c2 = i2 & 63;
        *(float2*)&a2s[r][2 * c2] = *(const float2*)(A2 + ((size_t)g * LL + r) * H + 2 * c2);
    }
    for (int iu = tid; iu < 16 * 64; iu += 256) {
        int r = iu >> 6, c = iu & 63;
        float2 v = up2(((const u32*)BxU)[(size_t)(n0g + r) * 64 + c]);
        *(float2*)&bxs[r][2 * c] = v;
    }
    if (tid < H) w2s[tid] = linNf_w[tid];
    __syncthreads();

    int n = tid & 15, tt = tid >> 4;
#pragma unroll
    for (int pass = 0; pass < 3; ++pass) {
        int t = tt + 16 * pass;
        float acc = 0.f;
#pragma unroll
        for (int kp = 0; kp < 64; ++kp) {
            float2 a2 = *(const float2*)&a2s[t][2 * kp];
            float2 bx = *(const float2*)&bxs[n][2 * kp];
            float2 w  = *(const float2*)&w2s[2 * kp];
            acc += w.x * fmaxf(a2.x + bx.x, 0.f) + w.y * fmaxf(a2.y + bx.y, 0.f);
        }
        logits[(size_t)(n0g + n) * LL + t] = acc;
    }
}

// ---------------- per-(graph,t) softmax over nodes; write output ----------------
__global__ __launch_bounds__(256) void k_softmax(const float* __restrict__ logits,
                                                 float* __restrict__ out) {
    __shared__ float lg[NPG][LL + 1];
    __shared__ float pm[4][LL], ps[4][LL];
    __shared__ float mv[LL], inv[LL];
    int b = blockIdx.x, tid = threadIdx.x;
    int n0 = b * NPG;
    for (int idx = tid; idx < NPG * LL; idx += 256) {
        int n = idx / LL, t = idx - n * LL;
        lg[n][t] = logits[(size_t)n0 * LL + idx];
    }
    __syncthreads();
    int t = tid & 63, seg = tid >> 6;
    if (t < LL) {
        float m = -1e30f;
        int nb = seg * 32;
        for (int n = nb; n < nb + 32; ++n) m = fmaxf(m, lg[n][t]);
        pm[seg][t] = m;
    }
    __syncthreads();
    if (tid < LL)
        mv[tid] = fmaxf(fmaxf(pm[0][tid], pm[1][tid]), fmaxf(pm[2][tid], pm[3][tid]));
    __syncthreads();
    if (t < LL) {
        float m = mv[t], s = 0.f;
        int nb = seg * 32;
        for (int n = nb; n < nb + 32; ++n) {
            float e = __expf(lg[n][t] - m);
            lg[n][t] = e;
            s += e;
        }
        ps[seg][t] = s;
    }
    __syncthreads();
    if (tid < LL)
        inv[tid] = 1.f / (ps[0][tid] + ps[1][tid] + ps[2][tid] + ps[3][tid]);
    __syncthreads();
    for (int idx = tid; idx < NPG * LL; idx += 256) {
        int n = idx / LL, tc = idx - n * LL;
        out[(size_t)BB * VA + (size_t)n0 * LL + idx] = lg[n][tc] * inv[tc];
    }
}

// ---------------- launch ----------------
extern "C" void kernel_launch(void* const* d_in, const int* in_sizes, int n_in,
                              void* d_out, int out_size, void* d_ws, size_t ws_size,
                              hipStream_t stream) {
    (void)in_sizes; (void)n_in; (void)out_size; (void)ws_size;
    const int*   nodeTypes    = (const int*)d_in[0];
    const int*   edge_index   = (const int*)d_in[1];
    const int*   edge_attr    = (const int*)d_in[2];
    const int*   nodes_bs     = (const int*)d_in[4];
    const int*   len_seq      = (const int*)d_in[5];
    const float* seq_in       = (const float*)d_in[6];
    const int*   action_input = (const int*)d_in[7];
    const float* emb_nodes    = (const float*)d_in[8];
    const float* emb_actions  = (const float*)d_in[9];
    const float* rgcn_rel     = (const float*)d_in[10];
    const float* rgcn_root    = (const float*)d_in[11];
    const float* rgcn_bias    = (const float*)d_in[12];
    const float* gru_w_ih     = (const float*)d_in[13];
    const float* gru_w_hh     = (const float*)d_in[14];
    const float* gru_b_ih     = (const float*)d_in[15];
    const float* gru_b_hh     = (const float*)d_in[16];
    const float* linA_w       = (const float*)d_in[17];
    const float* linA_b       = (const float*)d_in[18];
    const float* linAf_w      = (const float*)d_in[19];
    const float* linAf_b      = (const float*)d_in[20];
    const float* linN_w       = (const float*)d_in[21];
    const float* linN_b       = (const float*)d_in[22];
    const float* linNf_w      = (const float*)d_in[23];
    // linNf_b cancels in the softmax

    char* w = (char*)d_ws;
    float* x0      = (float*)(w + 0);          // [0,4MB) emb ping; dead after rgcn L3
    u16*   xwG     = (u16*)  (w + 0);          //   overlay (after L3): [0, 2,359,296)
    float* logitsW = (float*)(w + 0);          //   overlay (after k_gru): [0, 1,572,864)
    float* soutG   = (float*)(w + 2359296);    //   overlay (after L3): [.., 3,932,160)
    float* x1      = (float*)(w + 4194304);    // [4MB,8MB) final x f32 (live to end)
    float* igG     = (float*)(w + 8388608);    // [8MB, 9,961,472) shifted GRU input
    float* A2      = (float*)(w + 8388608);    //   overlay (igG dead before k_a2)
    u16*   BxU     = (u16*)  (w + 9961472);    // [9,961,472, 12,058,624)
    int*   bsum    = (int*)  (w + 9961472);    //   overlay on BxU (dead until k_bx)
    int*   boff    = (int*)  (w + 9962496);    //   overlay on BxU + 1 KB
    float* hGsum   = (float*)(w + 9969664);    //   overlay on BxU + 8 KB (dead by k_bx)
    int*   rowptr  = (int*)  (w + 11567104);   // dead after rgcn L3
    int*   fill    = (int*)  (w + 11829760);   // dead after scatter
    u16*   WTih    = (u16*)  (w + 11829760);   //   overlay fill; dead after k_xw
    float* hG      = (float*)(w + 12058624);   // 32 KB
    int*   colidx  = (int*)  (w + 12091904);   // dead after rgcn L3
    u16*   WT      = (u16*)  (w + 12616192);   // rgcn weights bf16 (tiled), 884,736 B

    float* out_f = (float*)d_out;

    k_init<<<dim3(4096), dim3(256), 0, stream>>>(nodeTypes, emb_nodes, x0, fill);
    k_hist<<<dim3(256), dim3(256), 0, stream>>>(edge_index, edge_attr, fill);
    k_scan1<<<dim3(256), dim3(256), 0, stream>>>(fill, bsum);
    k_scan2<<<dim3(1), dim3(256), 0, stream>>>(bsum, boff, rowptr);
    k_scan3<<<dim3(256), dim3(256), 0, stream>>>(boff, fill, rowptr);
    k_scatter<<<dim3(256), dim3(256), 0, stream>>>(edge_index, edge_attr, fill, colidx);
    k_wprep<<<dim3(1728), dim3(256), 0, stream>>>(rgcn_rel, rgcn_root, gru_w_ih,
                                                  WT, WTih, hGsum);

    const int rg_grid = NN / RGN;   // 512
    k_rgcn<<<dim3(rg_grid), dim3(256), 0, stream>>>(x0, x1,
        WT + 0 * 147456, rgcn_bias + 0 * H, rowptr, colidx, nullptr);
    k_rgcn<<<dim3(rg_grid), dim3(256), 0, stream>>>(x1, x0,
        WT + 1 * 147456, rgcn_bias + 1 * H, rowptr, colidx, nullptr);
    k_rgcn<<<dim3(rg_grid), dim3(256), 0, stream>>>(x0, x1,
        WT + 2 * 147456, rgcn_bias + 2 * H, rowptr, colidx, hGsum);
    // x_final = x1 (x0 region free from here)

    k_pool_act<<<dim3(BB), dim3(128), 0, stream>>>(hGsum, nodes_bs, linA_w, linA_b,
                                                   linAf_w, linAf_b, hG, out_f);
    k_seqpool<<<dim3(BB), dim3(256), 0, stream>>>(x1, seq_in, emb_actions, action_input, igG);
    k_xw<<<dim3(BB * LL / 16), dim3(256), 0, stream>>>(igG, WTih, gru_b_ih, xwG);
    k_gru<<<dim3(BB), dim3(768), 0, stream>>>(xwG, hG, gru_w_hh, gru_b_hh, len_seq, soutG);
    k_a2<<<dim3(BB * LL / 16), dim3(256), 0, stream>>>(soutG, linN_w, A2);
    k_bx<<<dim3(NN / 16), dim3(256), 0, stream>>>(x1, linN_w, linN_b, BxU);
    k_logits<<<dim3(BB * 8), dim3(256), 0, stream>>>(A2, BxU, linNf_w, logitsW);
    k_softmax<<<dim3(BB), dim3(256), 0, stream>>>(logitsW, out_f);
}

// Round 17
// 368.778 us; speedup vs baseline: 1.3329x; 1.0114x over previous
//
#include <hip/hip_runtime.h>
#include <hip/hip_bf16.h>

#define H   128
#define RR  8
#define NN  8192
#define BB  64
#define LL  48
#define EE  65536
#define NPG 128          // nodes per graph (N/B)
#define VA  64
#define NSEG (NN*RR)     // 65536

typedef unsigned short u16;
typedef unsigned int   u32;

__device__ __forceinline__ float b2f(u16 u) {
    union { u32 i; float f; } v; v.i = ((u32)u) << 16; return v.f;
}
__device__ __forceinline__ u16 f2b(float f) {
    union { float f; u32 i; } v; v.f = f;
    u32 x = v.i;
    return (u16)((x + 0x7fffu + ((x >> 16) & 1u)) >> 16);
}
__device__ __forceinline__ float2 up2(u32 p) {
    union { u32 i; float f; } a, b;
    a.i = p << 16; b.i = p & 0xffff0000u;
    return make_float2(a.f, b.f);
}
__device__ __forceinline__ u32 pk2(float a, float b) {
    return ((u32)f2b(b) << 16) | (u32)f2b(a);
}
__device__ __forceinline__ float rcpf(float x) { return __builtin_amdgcn_rcpf(x); }

typedef __attribute__((ext_vector_type(8))) short bf16x8;
typedef __attribute__((ext_vector_type(4))) float f32x4;

// ---------------- init: zero seg counters + embed nodes (f32 out) ----------------
__global__ __launch_bounds__(256) void k_init(const int* __restrict__ nodeTypes,
                                              const float* __restrict__ emb_nodes,
                                              float* __restrict__ x0,
                                              int* __restrict__ fill) {
    int idx = blockIdx.x * 256 + threadIdx.x;
    if (idx < NSEG) fill[idx] = 0;
    if (idx < NN * H) {
        int n = idx >> 7, h = idx & (H - 1);
        x0[idx] = emb_nodes[(size_t)nodeTypes[n] * H + h];
    }
}

// ---------------- histogram of (dst,rel) segments ----------------
__global__ __launch_bounds__(256) void k_hist(const int* __restrict__ edge_index,
                                              const int* __restrict__ edge_attr,
                                              int* __restrict__ fill) {
    int e = blockIdx.x * 256 + threadIdx.x;
    if (e < EE) {
        int seg = edge_index[EE + e] * RR + edge_attr[e];
        atomicAdd(&fill[seg], 1);
    }
}

// ---------------- 3-stage parallel exclusive scan over 65536 counts ----------------
__global__ __launch_bounds__(256) void k_scan1(const int* __restrict__ fill,
                                               int* __restrict__ bsum) {
    __shared__ int red[4];
    int tid = threadIdx.x, lane = tid & 63, wv = tid >> 6;
    int v = fill[blockIdx.x * 256 + tid];
#pragma unroll
    for (int off = 32; off >= 1; off >>= 1) v += __shfl_down(v, off, 64);
    if (lane == 0) red[wv] = v;
    __syncthreads();
    if (tid == 0) bsum[blockIdx.x] = red[0] + red[1] + red[2] + red[3];
}

__global__ __launch_bounds__(256) void k_scan2(const int* __restrict__ bsum,
                                               int* __restrict__ boff,
                                               int* __restrict__ rowptr) {
    __shared__ int s[256];
    int tid = threadIdx.x;
    int v0 = bsum[tid];
    s[tid] = v0;
    __syncthreads();
    for (int off = 1; off < 256; off <<= 1) {
        int v = (tid >= off) ? s[tid - off] : 0;
        __syncthreads();
        s[tid] += v;
        __syncthreads();
    }
    boff[tid] = s[tid] - v0;           // exclusive
    if (tid == 255) rowptr[NSEG] = s[255];
}

__global__ __launch_bounds__(256) void k_scan3(const int* __restrict__ boff,
                                               int* __restrict__ fill,
                                               int* __restrict__ rowptr) {
    __shared__ int s[256];
    int tid = threadIdx.x;
    int g = blockIdx.x * 256 + tid;
    int c = fill[g];
    s[tid] = c;
    __syncthreads();
    for (int off = 1; off < 256; off <<= 1) {
        int v = (tid >= off) ? s[tid - off] : 0;
        __syncthreads();
        s[tid] += v;
        __syncthreads();
    }
    int r = boff[blockIdx.x] + s[tid] - c;
    rowptr[g] = r;
    fill[g] = r;    // becomes scatter cursor
}

// ---------------- scatter edges into CSR ----------------
__global__ __launch_bounds__(256) void k_scatter(const int* __restrict__ edge_index,
                                                 const int* __restrict__ edge_attr,
                                                 int* __restrict__ fill,
                                                 int* __restrict__ colidx) {
    int e = blockIdx.x * 256 + threadIdx.x;
    if (e < EE) {
        int seg = edge_index[EE + e] * RR + edge_attr[e];
        int pos = atomicAdd(&fill[seg], 1);
        colidx[pos] = edge_index[e];   // src
    }
}

// ---------------- merged weight prep: fragment-tiled WT + W_ih bf16 + hGsum zero ----------------
__global__ __launch_bounds__(256) void k_wprep(const float* __restrict__ rel,
                                               const float* __restrict__ root,
                                               const float* __restrict__ w_ih,
                                               u16* __restrict__ WTt,
                                               u16* __restrict__ WTih,
                                               float* __restrict__ hGsum) {
    int idx = blockIdx.x * 256 + threadIdx.x;
    if (idx < 384 * H) WTih[idx] = f2b(w_ih[idx]);
    if (idx < BB * H) hGsum[idx] = 0.f;
    if (idx >= 3 * 147456) return;
    int li  = idx / 147456;
    int rem = idx - li * 147456;
    int tile = rem / 36864;
    int r2   = rem - tile * 36864;
    int ks   = r2 / 1024;
    int r3   = r2 - ks * 1024;
    int sub  = r3 >> 9;
    int r4   = r3 & 511;
    int lane = r4 >> 3, j = r4 & 7;
    int col = tile * 32 + sub * 16 + (lane & 15);
    int k   = ks * 32 + (lane >> 4) * 8 + j;
    float v;
    if (k < 1024) v = rel[(((size_t)li * RR + (k >> 7)) * H + (k & 127)) * H + col];
    else          v = root[((size_t)li * H + (k - 1024)) * H + col];
    WTt[idx] = f2b(v);
}

// ---------------- one RGCN layer: segment-parallel register gather + bf16 MFMA GEMM ----------------
#define RGN 16           // nodes per block; grid = 512
#define EPRE 512

__global__ __launch_bounds__(256) void k_rgcn(const float* __restrict__ xin,
                                              float* __restrict__ xout,
                                              const u16* __restrict__ WTt,    // fragment-tiled
                                              const float* __restrict__ bias, // [H]
                                              const int* __restrict__ rowptr,
                                              const int* __restrict__ colidx,
                                              float* __restrict__ hGsum) {   // null except L3
    __shared__ u32 ab[RGN * 580];          // 37.1 KB bf16-packed A (row stride 580)
    __shared__ int begs[RGN * RR + 1];
    __shared__ int eidx[EPRE];
    int tid = threadIdx.x, wv = tid >> 6, lane = tid & 63;
    int n0 = blockIdx.x * RGN, segbase = n0 * RR;

    if (tid <= RGN * RR) begs[tid] = rowptr[segbase + tid];
    __syncthreads();
    int E0 = begs[0], ne = begs[RGN * RR] - E0;
    for (int i = tid; i < ne && i < EPRE; i += 256) eidx[i] = colidx[E0 + i];
    __syncthreads();

    // phase A: wave per segment; lanes cover H via float2; mean in registers; packed write
    for (int s = wv; s < RGN * RR; s += 4) {
        int beg = begs[s], end = begs[s + 1];
        float a0 = 0.f, a1 = 0.f;
        for (int e = beg; e < end; ++e) {
            int off = e - E0;
            int src = (off < EPRE) ? eidx[off] : colidx[e];
            float2 v = ((const float2*)(xin + (size_t)src * H))[lane];
            a0 += v.x; a1 += v.y;
        }
        float inv = 1.f / fmaxf((float)(end - beg), 1.f);
        ab[(s >> 3) * 580 + ((s & 7) << 6) + lane] = pk2(a0 * inv, a1 * inv);
    }
    // root block: k-pair slots 512..575
    for (int i = wv; i < RGN; i += 4) {
        const float* xr = xin + (size_t)(n0 + i) * H + 2 * lane;
        ab[i * 580 + 512 + lane] = pk2(xr[0], xr[1]);
    }
    __syncthreads();

    // MFMA GEMM: wave = 32-col tile; 36 ksteps of 16x16x32 bf16, 2 n-subtiles
    int m = lane & 15, quad = lane >> 4;
    int colbase = wv * 32;
    const u32* aP = ab + m * 580 + quad * 4;
    const u32* bT = (const u32*)WTt + (size_t)wv * 36 * 512 + lane * 4;
    f32x4 acc0 = {0.f, 0.f, 0.f, 0.f}, acc1 = {0.f, 0.f, 0.f, 0.f};
    bf16x8 b0c = *(const bf16x8*)bT;
    bf16x8 b1c = *(const bf16x8*)(bT + 256);
    for (int ks = 0; ks < 36; ++ks) {
        bf16x8 b0n, b1n;
        if (ks < 35) {
            b0n = *(const bf16x8*)(bT + (ks + 1) * 512);
            b1n = *(const bf16x8*)(bT + (ks + 1) * 512 + 256);
        }
        bf16x8 a = *(const bf16x8*)(aP + ks * 16);
        acc0 = __builtin_amdgcn_mfma_f32_16x16x32_bf16(a, b0c, acc0, 0, 0, 0);
        acc1 = __builtin_amdgcn_mfma_f32_16x16x32_bf16(a, b1c, acc1, 0, 0, 0);
        b0c = b0n; b1c = b1n;
    }
    int c0 = colbase + m, c1 = c0 + 16;
    float bv0 = bias[c0], bv1 = bias[c1];
    float so0 = 0.f, so1 = 0.f;
#pragma unroll
    for (int rg = 0; rg < 4; ++rg) {
        int n = n0 + quad * 4 + rg;
        float o0 = fmaxf(acc0[rg] + bv0, 0.f);
        float o1 = fmaxf(acc1[rg] + bv1, 0.f);
        xout[(size_t)n * H + c0] = o0;
        xout[(size_t)n * H + c1] = o1;
        so0 += o0; so1 += o1;
    }
    if (hGsum) {      // fused mean-pool partial sums (layer 3 only)
        so0 += __shfl_xor(so0, 16, 64);
        so0 += __shfl_xor(so0, 32, 64);
        so1 += __shfl_xor(so1, 16, 64);
        so1 += __shfl_xor(so1, 32, 64);
        if (quad == 0) {
            int g = n0 >> 7;
            atomicAdd(&hGsum[g * H + c0], so0);
            atomicAdd(&hGsum[g * H + c1], so1);
        }
    }
}

// ---------------- action head (reads fused pool sums; writes divided hG) ----------------
__global__ __launch_bounds__(128) void k_pool_act(const float* __restrict__ hGsum,
                                                  const int* __restrict__ nodes_bs,
                                                  const float* __restrict__ linA_w,
                                                  const float* __restrict__ linA_b,
                                                  const float* __restrict__ linAf_w,
                                                  const float* __restrict__ linAf_b,
                                                  float* __restrict__ hG,
                                                  float* __restrict__ out) {
    __shared__ float hgs[H], t1[H];
    int b = blockIdx.x, h = threadIdx.x;
    float hg = hGsum[(size_t)b * H + h] / (float)nodes_bs[b];
    hG[(size_t)b * H + h] = hg;
    hgs[h] = hg;
    __syncthreads();
    float acc = linA_b[h];
    const float* wr = linA_w + (size_t)h * H;
    for (int k = 0; k < H; ++k) acc += wr[k] * hgs[k];
    t1[h] = fmaxf(acc, 0.f);
    __syncthreads();
    if (h < VA) {
        float a = linAf_b[h];
        const float* w2 = linAf_w + (size_t)h * H;
        for (int k = 0; k < H; ++k) a += w2[k] * t1[k];
        out[(size_t)b * VA + h] = a;
    }
}

// ---------------- sequence pooling -> SHIFTED GRU input igG ----------------
__global__ __launch_bounds__(256) void k_seqpool(const float* __restrict__ xf,
                                                 const float* __restrict__ seq,
                                                 const float* __restrict__ emb_actions,
                                                 const int* __restrict__ action_input,
                                                 float* __restrict__ igG) {
    __shared__ float xg[64][H];        // 32 KB
    __shared__ u16 lists[LL][64];      // 6 KB
    __shared__ int cnts[LL];
    int b = blockIdx.x, tid = threadIdx.x;
    int col = tid & 127, tg = tid >> 7;
    float acc[24];
#pragma unroll
    for (int m = 0; m < 24; ++m) acc[m] = 0.f;

    for (int chunk = 0; chunk < 2; ++chunk) {
        int i0 = b * NPG + chunk * 64;
        __syncthreads();
        if (tid < LL) cnts[tid] = 0;
        __syncthreads();
        for (int idx = tid; idx < 64 * H / 4; idx += 256)
            ((float4*)&xg[0][0])[idx] = ((const float4*)(xf + (size_t)i0 * H))[idx];
        for (int idx = tid; idx < 64 * LL; idx += 256) {
            int i = idx / LL, t = idx - i * LL;
            if (seq[(size_t)(i0 + i) * LL + t] != 0.f) {
                int p = atomicAdd(&cnts[t], 1);
                lists[t][p] = (u16)i;
            }
        }
        __syncthreads();
        for (int m = 0; m < 24; ++m) {
            int t = tg + 2 * m;
            int c = cnts[t];
            float a = acc[m];
            for (int p = 0; p < c; ++p) a += xg[lists[t][p]][col];
            acc[m] = a;
        }
    }
    if (tid < H)
        igG[((size_t)b * LL) * H + tid] = emb_actions[(size_t)action_input[b] * H + tid];
#pragma unroll
    for (int m = 0; m < 24; ++m) {
        int t = tg + 2 * m;
        if (t < LL - 1)
            igG[((size_t)b * LL + t + 1) * H + col] = acc[m];
    }
}

// ---------------- xw GEMM: xwG[3072][384] = igG @ W_ih^T + b_ih (bf16 out, MFMA) ----------------
__global__ __launch_bounds__(256) void k_xw(const float* __restrict__ igG,
                                            const u16* __restrict__ WTih,
                                            const float* __restrict__ b_ih,
                                            u16* __restrict__ xwG) {
    __shared__ u32 ab[16 * 68];        // 4.35 KB, stride 68
    int tid = threadIdx.x, wv = tid >> 6, lane = tid & 63;
    int n0 = blockIdx.x * 16;
    for (int s = tid; s < 16 * 64; s += 256) {
        int row = s >> 6, kp = s & 63;
        float2 v = *(const float2*)(igG + (size_t)(n0 + row) * H + 2 * kp);
        ab[row * 68 + kp] = pk2(v.x, v.y);
    }
    __syncthreads();
    int m = lane & 15, quad = lane >> 4;
    const u32* aP = ab + m * 68 + quad * 4;
    f32x4 acc[6];
#pragma unroll
    for (int i = 0; i < 6; ++i) acc[i] = (f32x4){0.f, 0.f, 0.f, 0.f};
#pragma unroll
    for (int ks = 0; ks < 4; ++ks) {
        bf16x8 a = *(const bf16x8*)(aP + ks * 16);
#pragma unroll
        for (int tc = 0; tc < 6; ++tc) {
            int colr = wv * 96 + tc * 16 + m;
            bf16x8 bfr = *(const bf16x8*)((const u32*)WTih + (size_t)colr * 64 + quad * 4 + ks * 16);
            acc[tc] = __builtin_amdgcn_mfma_f32_16x16x32_bf16(a, bfr, acc[tc], 0, 0, 0);
        }
    }
#pragma unroll
    for (int tc = 0; tc < 6; ++tc) {
        int c = wv * 96 + tc * 16 + m;
        float bv = b_ih[c];
#pragma unroll
        for (int rg = 0; rg < 4; ++rg) {
            int r = n0 + quad * 4 + rg;
            xwG[(size_t)r * 384 + c] = f2b(acc[tc][rg] + bv);
        }
    }
}

// ---------------- GRU: sequential steps; latency-optimized recurrence ----------------
// (a) 4-way split accumulation chains; (b) rcp-based sigmoid / exp-based tanh;
// (c) sout history in LDS, single global dump (no per-step vmcnt drain at barriers).
__global__ __launch_bounds__(768) void k_gru(const u16* __restrict__ xwG,
                                             const float* __restrict__ hG,
                                             const float* __restrict__ w_hh,
                                             const float* __restrict__ b_hh,
                                             const int* __restrict__ len_seq,
                                             float* __restrict__ soutG) {
    __shared__ float xws[LL][3 * H];    // 73.7 KB
    __shared__ float souts[LL][H];      // 24.6 KB
    __shared__ float hbuf[H];
    __shared__ float gh[3 * H];
    int b = blockIdx.x, tid = threadIdx.x;

    const u16* src = xwG + (size_t)b * LL * 384;
    float* xf = &xws[0][0];
    for (int idx = tid; idx < LL * 384; idx += 768) xf[idx] = b2f(src[idx]);
    if (tid < H) hbuf[tid] = hG[(size_t)b * H + tid];

    int j = tid >> 1, half = tid & 1;
    u32 wh[32];
    {
        const float* wp = w_hh + (size_t)j * H + 2 * half;   // elements 4k+2h, 4k+2h+1
#pragma unroll
        for (int k = 0; k < 32; ++k) wh[k] = pk2(wp[4 * k], wp[4 * k + 1]);
    }
    float bhh = b_hh[j];
    int ls = len_seq[b];
    __syncthreads();

    for (int t = 0; t < LL; ++t) {
        const float* hb = hbuf + 2 * half;
        float p[4] = {0.f, 0.f, 0.f, 0.f};
#pragma unroll
        for (int k = 0; k < 32; ++k) {
            float2 w = up2(wh[k]);
            float2 h2 = *(const float2*)&hb[4 * k];
            p[k & 3] += w.x * h2.x + w.y * h2.y;
        }
        float a = (p[0] + p[1]) + (p[2] + p[3]);
        a += __shfl_xor(a, 1, 64);
        if (half == 0) gh[j] = a + bhh;
        __syncthreads();
        if (tid < H) {
            float rg = rcpf(1.f + __expf(-(xws[t][tid] + gh[tid])));
            float zg = rcpf(1.f + __expf(-(xws[t][tid + H] + gh[tid + H])));
            float u  = xws[t][tid + 2 * H] + rg * gh[tid + 2 * H];
            float ng = 1.f - 2.f * rcpf(__expf(2.f * u) + 1.f);
            float hnew = (1.f - zg) * ng + zg * hbuf[tid];
            hbuf[tid] = hnew;
            souts[t][tid] = hnew;
        }
        __syncthreads();
    }

    // single coalesced dump (pad_packed mask applied here)
    for (int idx = tid; idx < LL * H; idx += 768) {
        int t = idx >> 7, hh = idx & 127;
        soutG[((size_t)b * LL + t) * H + hh] = (t < ls) ? souts[t][hh] : 0.f;
    }
}

// ---------------- A2[row,:] = W1a @ sout[row]  (rows = b*48+t), f32 out ----------------
__global__ __launch_bounds__(256) void k_a2(const float* __restrict__ soutG,
                                            const float* __restrict__ linN_w,
                                            float* __restrict__ A2) {
    __shared__ float wb[32][130];
    __shared__ float xl[16][H];
    int tid = threadIdx.x;
    int n0 = blockIdx.x * 16;
    for (int idx = tid; idx < 16 * H; idx += 256)
        xl[idx >> 7][idx & 127] = soutG[(size_t)n0 * H + idx];
    int col = tid & 127, g = tid >> 7;
    float acc[8] = {0.f, 0.f, 0.f, 0.f, 0.f, 0.f, 0.f, 0.f};
    for (int c = 0; c < 4; ++c) {
        int k0 = c * 32;
        __syncthreads();
        for (int idx = tid; idx < 32 * H; idx += 256) {
            int r = idx >> 5, kk = idx & 31;
            wb[kk][r] = linN_w[(size_t)r * (2 * H) + k0 + kk];
        }
        __syncthreads();
#pragma unroll
        for (int kk = 0; kk < 32; ++kk) {
            float w = wb[kk][col];
#pragma unroll
            for (int j = 0; j < 8; ++j) acc[j] += xl[g * 8 + j][k0 + kk] * w;
        }
    }
#pragma unroll
    for (int j = 0; j < 8; ++j)
        A2[(size_t)(n0 + g * 8 + j) * H + col] = acc[j];
}

// ---------------- Bx[n,:] = W1b @ x[n] + linN_b (bf16 out) ----------------
__global__ __launch_bounds__(256) void k_bx(const float* __restrict__ xf,
                                            const float* __restrict__ linN_w,
                                            const float* __restrict__ linN_b,
                                            u16* __restrict__ BxU) {
    __shared__ float wb[32][130];
    __shared__ float xl[16][H];
    int tid = threadIdx.x;
    int n0 = blockIdx.x * 16;
    for (int idx = tid; idx < 16 * H; idx += 256)
        xl[idx >> 7][idx & 127] = xf[(size_t)n0 * H + idx];
    int col = tid & 127, g = tid >> 7;
    float bv = linN_b[col];
    float acc[8] = {bv, bv, bv, bv, bv, bv, bv, bv};
    for (int c = 0; c < 4; ++c) {
        int k0 = c * 32;
        __syncthreads();
        for (int idx = tid; idx < 32 * H; idx += 256) {
            int r = idx >> 5, kk = idx & 31;
            wb[kk][r] = linN_w[(size_t)r * (2 * H) + H + k0 + kk];
        }
        __syncthreads();
#pragma unroll
        for (int kk = 0; kk < 32; ++kk) {
            float w = wb[kk][col];
#pragma unroll
            for (int j = 0; j < 8; ++j) acc[j] += xl[g * 8 + j][k0 + kk] * w;
        }
    }
#pragma unroll
    for (int j = 0; j < 8; ++j)
        BxU[(size_t)(n0 + g * 8 + j) * H + col] = f2b(acc[j]);
}

// ---------------- logits[n][t] = sum_k w2[k]*relu(A2[t][k]+Bx[n][k]) ----------------
__global__ __launch_bounds__(256) void k_logits(const float* __restrict__ A2,
                                                const u16* __restrict__ BxU,
                                                const float* __restrict__ linNf_w,
                                                float* __restrict__ logits) {
    __shared__ float a2s[LL][130];
    __shared__ float bxs[16][130];
    __shared__ float w2s[H];
    int tid = threadIdx.x;
    int g = blockIdx.x >> 3, tile = blockIdx.x & 7;
    int n0g = g * NPG + tile * 16;

    for (int i2 = tid; i2 < LL * 64; i2 += 256) {
        int r = i2 >> 6, c2 = i2 & 63;
        *(float2*)&a2s[r][2 * c2] = *(const float2*)(A2 + ((size_t)g * LL + r) * H + 2 * c2);
    }
    for (int iu = tid; iu < 16 * 64; iu += 256) {
        int r = iu >> 6, c = iu & 63;
        float2 v = up2(((const u32*)BxU)[(size_t)(n0g + r) * 64 + c]);
        *(float2*)&bxs[r][2 * c] = v;
    }
    if (tid < H) w2s[tid] = linNf_w[tid];
    __syncthreads();

    int n = tid & 15, tt = tid >> 4;
#pragma unroll
    for (int pass = 0; pass < 3; ++pass) {
        int t = tt + 16 * pass;
        float acc = 0.f;
#pragma unroll
        for (int kp = 0; kp < 64; ++kp) {
            float2 a2 = *(const float2*)&a2s[t][2 * kp];
            float2 bx = *(const float2*)&bxs[n][2 * kp];
            float2 w  = *(const float2*)&w2s[2 * kp];
            acc += w.x * fmaxf(a2.x + bx.x, 0.f) + w.y * fmaxf(a2.y + bx.y, 0.f);
        }
        logits[(size_t)(n0g + n) * LL + t] = acc;
    }
}

// ---------------- per-(graph,t) softmax over nodes; write output ----------------
__global__ __launch_bounds__(256) void k_softmax(const float* __restrict__ logits,
                                                 float* __restrict__ out) {
    __shared__ float lg[NPG][LL + 1];
    __shared__ float pm[4][LL], ps[4][LL];
    __shared__ float mv[LL], inv[LL];
    int b = blockIdx.x, tid = threadIdx.x;
    int n0 = b * NPG;
    for (int idx = tid; idx < NPG * LL; idx += 256) {
        int n = idx / LL, t = idx - n * LL;
        lg[n][t] = logits[(size_t)n0 * LL + idx];
    }
    __syncthreads();
    int t = tid & 63, seg = tid >> 6;
    if (t < LL) {
        float m = -1e30f;
        int nb = seg * 32;
        for (int n = nb; n < nb + 32; ++n) m = fmaxf(m, lg[n][t]);
        pm[seg][t] = m;
    }
    __syncthreads();
    if (tid < LL)
        mv[tid] = fmaxf(fmaxf(pm[0][tid], pm[1][tid]), fmaxf(pm[2][tid], pm[3][tid]));
    __syncthreads();
    if (t < LL) {
        float m = mv[t], s = 0.f;
        int nb = seg * 32;
        for (int n = nb; n < nb + 32; ++n) {
            float e = __expf(lg[n][t] - m);
            lg[n][t] = e;
            s += e;
        }
        ps[seg][t] = s;
    }
    __syncthreads();
    if (tid < LL)
        inv[tid] = 1.f / (ps[0][tid] + ps[1][tid] + ps[2][tid] + ps[3][tid]);
    __syncthreads();
    for (int idx = tid; idx < NPG * LL; idx += 256) {
        int n = idx / LL, tc = idx - n * LL;
        out[(size_t)BB * VA + (size_t)n0 * LL + idx] = lg[n][tc] * inv[tc];
    }
}

// ---------------- launch ----------------
extern "C" void kernel_launch(void* const* d_in, const int* in_sizes, int n_in,
                              void* d_out, int out_size, void* d_ws, size_t ws_size,
                              hipStream_t stream) {
    (void)in_sizes; (void)n_in; (void)out_size; (void)ws_size;
    const int*   nodeTypes    = (const int*)d_in[0];
    const int*   edge_index   = (const int*)d_in[1];
    const int*   edge_attr    = (const int*)d_in[2];
    const int*   nodes_bs     = (const int*)d_in[4];
    const int*   len_seq      = (const int*)d_in[5];
    const float* seq_in       = (const float*)d_in[6];
    const int*   action_input = (const int*)d_in[7];
    const float* emb_nodes    = (const float*)d_in[8];
    const float* emb_actions  = (const float*)d_in[9];
    const float* rgcn_rel     = (const float*)d_in[10];
    const float* rgcn_root    = (const float*)d_in[11];
    const float* rgcn_bias    = (const float*)d_in[12];
    const float* gru_w_ih     = (const float*)d_in[13];
    const float* gru_w_hh     = (const float*)d_in[14];
    const float* gru_b_ih     = (const float*)d_in[15];
    const float* gru_b_hh     = (const float*)d_in[16];
    const float* linA_w       = (const float*)d_in[17];
    const float* linA_b       = (const float*)d_in[18];
    const float* linAf_w      = (const float*)d_in[19];
    const float* linAf_b      = (const float*)d_in[20];
    const float* linN_w       = (const float*)d_in[21];
    const float* linN_b       = (const float*)d_in[22];
    const float* linNf_w      = (const float*)d_in[23];
    // linNf_b cancels in the softmax

    char* w = (char*)d_ws;
    float* x0      = (float*)(w + 0);          // [0,4MB) emb ping; dead after rgcn L3
    u16*   xwG     = (u16*)  (w + 0);          //   overlay (after L3): [0, 2,359,296)
    float* logitsW = (float*)(w + 0);          //   overlay (after k_gru): [0, 1,572,864)
    float* soutG   = (float*)(w + 2359296);    //   overlay (after L3): [.., 3,932,160)
    float* x1      = (float*)(w + 4194304);    // [4MB,8MB) final x f32 (live to end)
    float* igG     = (float*)(w + 8388608);    // [8MB, 9,961,472) shifted GRU input
    float* A2      = (float*)(w + 8388608);    //   overlay (igG dead before k_a2)
    u16*   BxU     = (u16*)  (w + 9961472);    // [9,961,472, 12,058,624)
    int*   bsum    = (int*)  (w + 9961472);    //   overlay on BxU (dead until k_bx)
    int*   boff    = (int*)  (w + 9962496);    //   overlay on BxU + 1 KB
    float* hGsum   = (float*)(w + 9969664);    //   overlay on BxU + 8 KB (dead by k_bx)
    int*   rowptr  = (int*)  (w + 11567104);   // dead after rgcn L3
    int*   fill    = (int*)  (w + 11829760);   // dead after scatter
    u16*   WTih    = (u16*)  (w + 11829760);   //   overlay fill; dead after k_xw
    float* hG      = (float*)(w + 12058624);   // 32 KB
    int*   colidx  = (int*)  (w + 12091904);   // dead after rgcn L3
    u16*   WT      = (u16*)  (w + 12616192);   // rgcn weights bf16 (tiled), 884,736 B

    float* out_f = (float*)d_out;

    k_init<<<dim3(4096), dim3(256), 0, stream>>>(nodeTypes, emb_nodes, x0, fill);
    k_hist<<<dim3(256), dim3(256), 0, stream>>>(edge_index, edge_attr, fill);
    k_scan1<<<dim3(256), dim3(256), 0, stream>>>(fill, bsum);
    k_scan2<<<dim3(1), dim3(256), 0, stream>>>(bsum, boff, rowptr);
    k_scan3<<<dim3(256), dim3(256), 0, stream>>>(boff, fill, rowptr);
    k_scatter<<<dim3(256), dim3(256), 0, stream>>>(edge_index, edge_attr, fill, colidx);
    k_wprep<<<dim3(1728), dim3(256), 0, stream>>>(rgcn_rel, rgcn_root, gru_w_ih,
                                                  WT, WTih, hGsum);

    const int rg_grid = NN / RGN;   // 512
    k_rgcn<<<dim3(rg_grid), dim3(256), 0, stream>>>(x0, x1,
        WT + 0 * 147456, rgcn_bias + 0 * H, rowptr, colidx, nullptr);
    k_rgcn<<<dim3(rg_grid), dim3(256), 0, stream>>>(x1, x0,
        WT + 1 * 147456, rgcn_bias + 1 * H, rowptr, colidx, nullptr);
    k_rgcn<<<dim3(rg_grid), dim3(256), 0, stream>>>(x0, x1,
        WT + 2 * 147456, rgcn_bias + 2 * H, rowptr, colidx, hGsum);
    // x_final = x1 (x0 region free from here)

    k_pool_act<<<dim3(BB), dim3(128), 0, stream>>>(hGsum, nodes_bs, linA_w, linA_b,
                                                   linAf_w, linAf_b, hG, out_f);
    k_seqpool<<<dim3(BB), dim3(256), 0, stream>>>(x1, seq_in, emb_actions, action_input, igG);
    k_xw<<<dim3(BB * LL / 16), dim3(256), 0, stream>>>(igG, WTih, gru_b_ih, xwG);
    k_gru<<<dim3(BB), dim3(768), 0, stream>>>(xwG, hG, gru_w_hh, gru_b_hh, len_seq, soutG);
    k_a2<<<dim3(BB * LL / 16), dim3(256), 0, stream>>>(soutG, linN_w, A2);
    k_bx<<<dim3(NN / 16), dim3(256), 0, stream>>>(x1, linN_w, linN_b, BxU);
    k_logits<<<dim3(BB * 8), dim3(256), 0, stream>>>(A2, BxU, linNf_w, logitsW);
    k_softmax<<<dim3(BB), dim3(256), 0, stream>>>(logitsW, out_f);
}